// Round 3
// baseline (243.281 us; speedup 1.0000x reference)
//
#include <hip/hip_runtime.h>
#include <hip/hip_fp16.h>
#include <math.h>

// FrFT (Ozaktas, 0.5<a<1.5): x[256,4096] f32, order f32 -> Re(complex64) f32
// out[b*4096+j]. R16: in-block split-K (LDS-atomic reduce) for 4 waves/SIMD,
// Toeplitz shift-reuse for s1 weights, fm=4 amortization for s2 cos weights.
//
//   s1_full: xiT[b,s] = sum_i x[b,i]*w1(s-i)  (K=4096)
//     512 blocks x 8 waves: tile 32b x 64s (fs=4 @ s-stride 32), K split 8.
//     w1 frags: frag(f,st+1)=frag(f-1,st) -> 4-deep shift chain, 1 fresh/step.
//   s2_full: out[b,j] = scale*[sum even + sum odd]  (K=8191)
//     256 blocks x 16 waves: tile 64b x 64j (fm=4,fj=4), K split 16.
//     cos-weight frag reused across 4 A-frags (2 cos/MFMA).
//   Both: partials ds_add_f32 into an LDS tile, barrier, vector store.
//   XCD swizzle groups same-b-slice blocks per XCD (x slice L2-resident).
// Numerics identical to proven R14/R15 (quadratic phase, __cosf, __fdividef).

#define NN 4096
#define BB 256
#define KK (2*NN - 1)

typedef unsigned int uint;
typedef __attribute__((ext_vector_type(4))) float f32x4;
typedef __attribute__((ext_vector_type(8))) _Float16 half8;
typedef __attribute__((ext_vector_type(4))) _Float16 half4;

struct LitConsts { float c, q, scale, pe; };

__device__ __forceinline__ LitConsts get_lit(const float* order) {
  float a = order[0];
  float alpha = a * (float)M_PI * 0.5f;
  float sina = sinf(alpha);
  float tana2 = tanf(alpha * 0.5f);
  LitConsts L;
  L.c = (float)M_PI / (float)NN / sina / 4.0f;
  L.q = ((float)M_PI / (float)NN) * (tana2 * 0.25f);
  L.scale = sqrtf(L.c / (float)M_PI);
  L.pe = -(1.0f - a) * (float)M_PI * 0.25f;
  return L;
}

__device__ __forceinline__ float xload(const float* __restrict__ x, uint idx, uint cap) {
  return (idx < cap) ? x[idx] : 0.f;
}

// sinc-interp Toeplitz weight fragment: elements e=0..7 at t = t0 - e
__device__ __forceinline__ half8 mkw1(int t0) {
  const float C2PI = 0.63661977236758134f;
  half8 r;
#pragma unroll
  for (int e = 0; e < 8; ++e) {
    const int t = t0 - e;
    const float num = (t & 1) ? -C2PI : C2PI;
    r[e] = (_Float16)__fdividef(num, (float)(2 * t + 1));
  }
  return r;
}

// ---- stage 1: 512 blocks x 512 thr; tile 32b x 64s; K split 8 ----
__global__ __launch_bounds__(512, 4) void s1_full(const float* __restrict__ x,
                                                  _Float16* __restrict__ xiT) {
  __shared__ float red[2048];  // 32 rows x 64 cols, 8 KB
  const int tid = threadIdx.x;
  ((f32x4*)red)[tid] = (f32x4){0.f, 0.f, 0.f, 0.f};
  __syncthreads();

  const int id = blockIdx.x;
  const int bt = id & 7, sg = id >> 3;            // bt -> XCD (x slice resident)
  const int s0 = (sg >> 1) * 128 + (sg & 1) * 16; // sg in [0,64)
  const int b0 = bt * 32;
  const int wave = tid >> 6, lane = tid & 63;
  const int l15 = lane & 15, lhi = lane >> 4;
  const int sA = s0 + l15;

  f32x4 acc[2][4] = {};  // [fm(b)][fs(s @ stride 32)]
  int i0 = wave * 512 + lhi * 8;
  half8 w0 = mkw1(sA      - i0);
  half8 w1 = mkw1(sA + 32 - i0);
  half8 w2 = mkw1(sA + 64 - i0);
  half8 w3 = mkw1(sA + 96 - i0);

#pragma unroll 4
  for (int st = 0; st < 16; ++st) {
    half8 a[2];
#pragma unroll
    for (int fm = 0; fm < 2; ++fm) {
      const float* px = x + (size_t)(b0 + fm * 16 + l15) * NN + i0;
      f32x4 u0 = *(const f32x4*)px;
      f32x4 u1 = *(const f32x4*)(px + 4);
      half8 h;
#pragma unroll
      for (int e = 0; e < 4; ++e) { h[e] = (_Float16)u0[e]; h[e + 4] = (_Float16)u1[e]; }
      a[fm] = h;
    }
#pragma unroll
    for (int fm = 0; fm < 2; ++fm) {
      acc[fm][0] = __builtin_amdgcn_mfma_f32_16x16x32_f16(a[fm], w0, acc[fm][0], 0, 0, 0);
      acc[fm][1] = __builtin_amdgcn_mfma_f32_16x16x32_f16(a[fm], w1, acc[fm][1], 0, 0, 0);
      acc[fm][2] = __builtin_amdgcn_mfma_f32_16x16x32_f16(a[fm], w2, acc[fm][2], 0, 0, 0);
      acc[fm][3] = __builtin_amdgcn_mfma_f32_16x16x32_f16(a[fm], w3, acc[fm][3], 0, 0, 0);
    }
    i0 += 32;
    w3 = w2; w2 = w1; w1 = w0; w0 = mkw1(sA - i0);  // Toeplitz shift
  }

  // in-block split-K combine via LDS atomics
#pragma unroll
  for (int fm = 0; fm < 2; ++fm) {
    const int row = fm * 16 + lhi * 4;
#pragma unroll
    for (int fs = 0; fs < 4; ++fs) {
      const int cc = fs * 16 + l15;
#pragma unroll
      for (int rr = 0; rr < 4; ++rr)
        atomicAdd(&red[(row + rr) * 64 + cc], acc[fm][fs][rr]);
    }
  }
  __syncthreads();

  const int o = tid * 4;
  const int row = o >> 6, cc = o & 63;
  const int s = s0 + (cc >> 4) * 32 + (cc & 15);
  half4 h;
#pragma unroll
  for (int e = 0; e < 4; ++e) h[e] = (_Float16)red[o + e];
  *(half4*)(xiT + (size_t)(b0 + row) * NN + s) = h;
}

// ---- stage 2 segment: one parity, 8 k-steps of this wave's chunk ----
template <int ODD>
__device__ __forceinline__ void s2_seg(const float* __restrict__ x,
                                       const _Float16* __restrict__ xiT,
                                       const LitConsts& L, const float P2,
                                       const float* jbase, const int* jl,
                                       int b0, int wave, int l15, int lhi,
                                       f32x4 acc[4][4]) {
#pragma unroll 2
  for (int st = 0; st < 8; ++st) {
    const int i0 = wave * 256 + st * 32 + lhi * 8;
    half8 a[4];
    if (ODD) {
#pragma unroll
      for (int fm = 0; fm < 4; ++fm)
        a[fm] = *(const half8*)(xiT + (size_t)(b0 + fm * 16 + l15) * NN + i0);
    } else {
#pragma unroll
      for (int fm = 0; fm < 4; ++fm) {
        const float* px = x + (size_t)(b0 + fm * 16 + l15) * NN + i0;
        f32x4 u0 = *(const f32x4*)px;
        f32x4 u1 = *(const f32x4*)(px + 4);
        half8 h;
#pragma unroll
        for (int e = 0; e < 4; ++e) { h[e] = (_Float16)u0[e]; h[e + 4] = (_Float16)u1[e]; }
        a[fm] = h;
      }
    }
    const int r0 = 2 * i0 + ODD;
    const int k0 = r0 - (NN - 1);
    const float bk = -L.q * (float)(k0 * k0);
    const float qk0 = L.q * (float)k0;
#pragma unroll
    for (int fj = 0; fj < 4; ++fj) {
      const int d0 = 2 * jl[fj] - r0;
      const float P0 = fmaf(L.c, (float)(d0 * d0), jbase[fj] + bk);
      const float P1 = -4.f * fmaf(L.c, (float)d0, qk0);
      half8 bh;
#pragma unroll
      for (int e = 0; e < 8; ++e) {
        const float ef = (float)e;
        float ph = fmaf(ef, fmaf(ef, P2, P1), P0);
        float w = __cosf(ph);
        if (ODD && (i0 + e) > (NN - 2)) w = 0.f;  // r=8191 pad does not exist
        bh[e] = (_Float16)w;
      }
#pragma unroll
      for (int fm = 0; fm < 4; ++fm)
        acc[fm][fj] = __builtin_amdgcn_mfma_f32_16x16x32_f16(a[fm], bh, acc[fm][fj], 0, 0, 0);
    }
  }
}

// ---- stage 2: 256 blocks x 1024 thr; tile 64b x 64j; K split 16 ----
__global__ __launch_bounds__(1024, 4) void s2_full(const float* __restrict__ x,
                                                   const _Float16* __restrict__ xiT,
                                                   const float* __restrict__ order,
                                                   float* __restrict__ out) {
  __shared__ float red[4096];  // 64 x 64 tile, 16 KB
  const int tid = threadIdx.x;
  ((f32x4*)red)[tid] = (f32x4){0.f, 0.f, 0.f, 0.f};
  __syncthreads();

  const int id = blockIdx.x;
  const int xcd = id & 7, grp = id >> 3;
  const int bt = xcd >> 1, jt = (xcd & 1) | (grp << 1);  // same-bt -> 2 XCDs
  const int b0 = bt * 64, j0 = jt * 64;
  const int wave = tid >> 6, lane = tid & 63;
  const int l15 = lane & 15, lhi = lane >> 4;
  const LitConsts L = get_lit(order);
  const float P2 = 4.f * (L.c - L.q);

  int jl[4]; float jbase[4];
#pragma unroll
  for (int fj = 0; fj < 4; ++fj) {
    jl[fj] = j0 + fj * 16 + l15;
    const int n = 2 * jl[fj] - (NN - 1);
    jbase[fj] = fmaf(-L.q, (float)(n * n), L.pe);
  }

  f32x4 acc[4][4] = {};  // [fm(b)][fj(j)]
  s2_seg<0>(x, xiT, L, P2, jbase, jl, b0, wave, l15, lhi, acc);
  s2_seg<1>(x, xiT, L, P2, jbase, jl, b0, wave, l15, lhi, acc);

#pragma unroll
  for (int fm = 0; fm < 4; ++fm) {
    const int row = fm * 16 + lhi * 4;
#pragma unroll
    for (int fj = 0; fj < 4; ++fj) {
      const int col = fj * 16 + l15;
#pragma unroll
      for (int rr = 0; rr < 4; ++rr)
        atomicAdd(&red[(row + rr) * 64 + col], acc[fm][fj][rr]);
    }
  }
  __syncthreads();

  const int o = tid * 4;
  const int row = o >> 6, col = o & 63;
  f32x4 v;
#pragma unroll
  for (int e = 0; e < 4; ++e) v[e] = L.scale * red[o + e];
  *(f32x4*)(out + (size_t)(b0 + row) * NN + j0 + col) = v;
}

// ======================= R13 proven fallback (small ws) =======================

__global__ __launch_bounds__(256) void frft_interp(const float* __restrict__ x,
                                                   __half* __restrict__ xi,
                                                   int b_lo, int cnt,
                                                   uint xi_cap, uint x_cap) {
  __shared__ __align__(16) float wt1[32][64];
  __shared__ __align__(16) float xt[32][64];
  const int tid = threadIdx.x;
  const int s0 = blockIdx.x * 64, cb0 = blockIdx.y * 64;
  const int tx = tid & 15, ty = tid >> 4;
  const int ss0 = ty * 4, bb0 = tx * 4;

  float acc[4][4] = {};
  for (int i0 = 0; i0 < NN; i0 += 32) {
#pragma unroll
    for (int e = 0; e < 8; ++e) {
      int idx = tid + e * 256, qq = idx >> 6, ss = idx & 63;
      int t = s0 + ss - (i0 + qq);
      float sgn = (t & 1) ? -0.63661977236758134f : 0.63661977236758134f;
      wt1[qq][ss] = __fdividef(sgn, (float)(2 * t + 1));
    }
#pragma unroll
    for (int e = 0; e < 8; ++e) {
      int idx = tid + e * 256, qq = idx >> 6, bb = idx & 63;
      xt[qq][bb] = xload(x, (uint)(b_lo + cb0 + bb) * NN + (i0 + qq), x_cap);
    }
    __syncthreads();
#pragma unroll
    for (int qq = 0; qq < 32; ++qq) {
      float4 wv = *(const float4*)&wt1[qq][ss0];
      float4 uv = *(const float4*)&xt[qq][bb0];
      float w[4] = {wv.x, wv.y, wv.z, wv.w};
      float u[4] = {uv.x, uv.y, uv.z, uv.w};
#pragma unroll
      for (int aa = 0; aa < 4; ++aa)
#pragma unroll
        for (int cc = 0; cc < 4; ++cc) acc[aa][cc] = fmaf(w[aa], u[cc], acc[aa][cc]);
    }
    __syncthreads();
  }
#pragma unroll
  for (int aa = 0; aa < 4; ++aa) {
    int s = s0 + ss0 + aa;
    if (s < NN - 1) {
#pragma unroll
      for (int cc = 0; cc < 4; ++cc) {
        int cb = cb0 + bb0 + cc;
        if (cb < cnt) {
          uint o = (uint)s * (uint)cnt + (uint)cb;
          if (o < xi_cap) xi[o] = __float2half(acc[aa][cc]);
        }
      }
    }
  }
}

#define TJ 32
#define TB 64
#define TK 32
__global__ __launch_bounds__(256) void frft_gemm(const float* __restrict__ x,
                                                 const __half* __restrict__ xi,
                                                 const float* __restrict__ order,
                                                 float* __restrict__ out,
                                                 int b_lo, int cnt,
                                                 uint xi_cap, uint x_cap,
                                                 uint out_capf) {
  __shared__ __align__(16) float wt[TK][TJ];
  __shared__ __align__(16) float ut[TK][TB];
  const int tid = threadIdx.x;
  const int j0 = blockIdx.x * TJ, cb0 = blockIdx.y * TB;
  const int tx = tid & 15, ty = tid >> 4;
  const int jj0 = ty * 2, bb0 = tx * 4;

  LitConsts L = get_lit(order);
  float acc[2][4] = {};

  for (int r0 = 0; r0 < KK; r0 += TK) {
#pragma unroll
    for (int e = 0; e < 4; ++e) {
      int idx = tid + e * 256, qq = idx >> 5, jj = idx & 31;
      int r = r0 + qq;
      float wv = 0.f;
      if (r < KK) {
        int j = j0 + jj;
        int n = 2 * j - (NN - 1);
        int d = 2 * j - r;
        int k = r - (NN - 1);
        float base = fmaf(-L.q, (float)(n * n), L.pe);
        float ph = fmaf(L.c, (float)(d * d), fmaf(-L.q, (float)(k * k), base));
        wv = __cosf(ph);
      }
      wt[qq][jj] = wv;
    }
#pragma unroll
    for (int e = 0; e < 8; ++e) {
      int idx = tid + e * 256, qq = idx >> 6, bb = idx & 63;
      int r = r0 + qq, cb = cb0 + bb;
      float v = 0.f;
      if (r < KK && cb < cnt) {
        if (r & 1) {
          uint o = (uint)(r >> 1) * (uint)cnt + (uint)cb;
          v = (o < xi_cap) ? __half2float(xi[o]) : 0.f;
        } else {
          v = xload(x, (uint)(b_lo + cb) * NN + (uint)(r >> 1), x_cap);
        }
      }
      ut[qq][bb] = v;
    }
    __syncthreads();
#pragma unroll
    for (int qq = 0; qq < TK; ++qq) {
      float2 wv = *(const float2*)&wt[qq][jj0];
      float4 uv = *(const float4*)&ut[qq][bb0];
      float w[2] = {wv.x, wv.y};
      float u[4] = {uv.x, uv.y, uv.z, uv.w};
#pragma unroll
      for (int aa = 0; aa < 2; ++aa)
#pragma unroll
        for (int cc = 0; cc < 4; ++cc)
          acc[aa][cc] = fmaf(w[aa], u[cc], acc[aa][cc]);
    }
    __syncthreads();
  }

#pragma unroll
  for (int aa = 0; aa < 2; ++aa) {
    int j = j0 + jj0 + aa;
#pragma unroll
    for (int cc = 0; cc < 4; ++cc) {
      int cb = cb0 + bb0 + cc;
      if (cb < cnt) {
        uint idx = (uint)(b_lo + cb) * NN + (uint)j;
        if (idx < out_capf) out[idx] = L.scale * acc[aa][cc];
      }
    }
  }
}

__global__ __launch_bounds__(256) void frft_gemm1(const float* __restrict__ x,
                                                  const float* __restrict__ order,
                                                  float* __restrict__ out,
                                                  uint x_cap, uint out_capf) {
  __shared__ float xrow[NN];
  __shared__ float xio[NN - 1];
  __shared__ float red[4][64];
  const int tid = threadIdx.x;
  const int j0 = blockIdx.x * 64;
  LitConsts L = get_lit(order);

#pragma unroll
  for (int e = 0; e < 16; ++e) {
    int i = tid + e * 256;
    xrow[i] = xload(x, (uint)255 * NN + (uint)i, x_cap);
  }
  __syncthreads();
#pragma unroll
  for (int m = 0; m < 16; ++m) {
    int s = tid + m * 256;
    if (s < NN - 1) {
      float a0 = 0.f;
      for (int i = 0; i < NN; ++i) {
        int t = s - i;
        float sgn = (t & 1) ? -0.63661977236758134f : 0.63661977236758134f;
        a0 = fmaf(xrow[i], __fdividef(sgn, (float)(2 * t + 1)), a0);
      }
      xio[s] = a0;
    }
  }
  __syncthreads();

  const int ty = tid >> 6, jj = tid & 63;
  const int j = j0 + jj;
  const int n = 2 * j - (NN - 1);
  const float base = fmaf(-L.q, (float)(n * n), L.pe);
  float acc = 0.f;
  int rend = (ty + 1) * 2048; if (rend > KK) rend = KK;
  for (int r = ty * 2048; r < rend; ++r) {
    int d = 2 * j - r;
    int k = r - (NN - 1);
    float ph = fmaf(L.c, (float)(d * d), fmaf(-L.q, (float)(k * k), base));
    float u = (r & 1) ? xio[r >> 1] : xrow[r >> 1];
    acc = fmaf(__cosf(ph), u, acc);
  }
  red[ty][jj] = acc;
  __syncthreads();
  if (ty == 0) {
    float t = red[0][jj] + red[1][jj] + red[2][jj] + red[3][jj];
    uint idx = (uint)255 * NN + (uint)j;
    if (idx < out_capf) out[idx] = L.scale * t;
  }
}

extern "C" void kernel_launch(void* const* d_in, const int* in_sizes, int n_in,
                              void* d_out, int out_size, void* d_ws, size_t ws_size,
                              hipStream_t stream) {
  const float* x     = (const float*)d_in[0];
  const float* order = (const float*)d_in[1];
  float* outf = (float*)d_out;
  const uint x_cap    = (uint)in_sizes[0];
  const uint out_capf = (uint)out_size;
  const size_t ws_halves = ws_size / 2;

  // ---- R16 split-K-in-block MFMA path ----
  if (ws_size >= (size_t)NN * BB * 2 &&
      out_capf >= (uint)NN * BB && x_cap >= (uint)NN * BB) {
    _Float16* xiT = (_Float16*)d_ws;
    s1_full<<<dim3(512), 512, 0, stream>>>(x, xiT);
    s2_full<<<dim3(256), 1024, 0, stream>>>(x, xiT, order, outf);
    return;
  }

  // ---- R13 proven fallback paths ----
  if (ws_halves >= (size_t)(NN - 1) * BB) {
    uint xi_cap = (uint)((size_t)(NN - 1) * BB);
    frft_interp<<<dim3(64, 4), 256, 0, stream>>>(x, (__half*)d_ws, 0, BB, xi_cap, x_cap);
    frft_gemm<<<dim3(NN / TJ, BB / TB), 256, 0, stream>>>(x, (__half*)d_ws, order, outf,
                                                          0, BB, xi_cap, x_cap, out_capf);
  } else {
    struct Chunk { int lo, cnt; };
    const Chunk ch[6] = { {0,170}, {170,57}, {227,19}, {246,6}, {252,2}, {254,1} };
    for (int i = 0; i < 6; ++i) {
      const Chunk& c = ch[i];
      uint off = (uint)(c.lo + c.cnt) * (uint)NN;
      __half* xp = (__half*)(outf + off);
      size_t need = (size_t)(NN - 1) * (size_t)c.cnt;
      size_t avail = (out_capf > off) ? (size_t)(out_capf - off) * 2 : 0;
      uint xi_cap = (uint)(need < avail ? need : avail);
      frft_interp<<<dim3(64, (unsigned)((c.cnt + 63) / 64)), 256, 0, stream>>>(
          x, xp, c.lo, c.cnt, xi_cap, x_cap);
      frft_gemm<<<dim3(NN / TJ, (unsigned)((c.cnt + TB - 1) / TB)), 256, 0, stream>>>(
          x, xp, order, outf, c.lo, c.cnt, xi_cap, x_cap, out_capf);
    }
    if (ws_halves >= (size_t)(NN - 1)) {
      uint xi_cap = (uint)(NN - 1);
      frft_interp<<<dim3(64, 1), 256, 0, stream>>>(x, (__half*)d_ws, 255, 1, xi_cap, x_cap);
      frft_gemm<<<dim3(NN / TJ, 1), 256, 0, stream>>>(x, (__half*)d_ws, order, outf,
                                                      255, 1, xi_cap, x_cap, out_capf);
    } else {
      frft_gemm1<<<64, 256, 0, stream>>>(x, order, outf, x_cap, out_capf);
    }
  }
}

// Round 4
// 188.698 us; speedup vs baseline: 1.2893x; 1.2893x over previous
//
#include <hip/hip_runtime.h>
#include <hip/hip_fp16.h>
#include <math.h>

// FrFT (Ozaktas, 0.5<a<1.5): x[256,4096] f32, order f32 -> Re(complex64) f32
// out[b*4096+j]. R17: LDS-staged tiles kill the strided A-operand gathers
// that serialized R14-R16 (16KB-row-stride per-lane gathers -> L2 channel
// serialization, saturated at 1 wave/SIMD).
//
// Both stages: block = 256 thr (4 waves), tile 64 b-rows x 64 out-cols,
// full K per block in 128-wide chunks; chunk staged f16 in LDS (coalesced
// global row-sweeps, cvt once), double-buffered with early-issue/late-write
// prefetch; fragments via ds_read_b128 (stride 136 halves -> ~2-way, free).
// 4 waves split K (quarter each, weight frag amortized over fm=4 MFMAs);
// 2-phase LDS reduce (no atomics), coalesced vector stores.
//   s1_stage: xiT[b,s] = sum_i x[b,i]*w1(s-i)          (K=4096, f16 -> ws)
//   s2_stage: out[b,j] = scale*(even-r GEMM + odd-r GEMM), K=8191 fused.
// Weight math identical to proven R14-R16 (quadratic phase, __cosf,
// __fdividef); odd pad r=8191 weight-zeroed (xiT[*,4095] finite junk).

#define NN 4096
#define BB 256
#define KK (2*NN - 1)
#define CHW 128
#define UST 136   // f16 LDS row stride (272 B = 17*16: 16B-aligned, ~2-way banks)
#define RST 68    // f32 red row stride (272 B)

typedef unsigned int uint;
typedef __attribute__((ext_vector_type(4))) float f32x4;
typedef __attribute__((ext_vector_type(4))) uint u32x4;
typedef __attribute__((ext_vector_type(8))) _Float16 half8;

struct LitConsts { float c, q, scale, pe; };

__device__ __forceinline__ LitConsts get_lit(const float* order) {
  float a = order[0];
  float alpha = a * (float)M_PI * 0.5f;
  float sina = sinf(alpha);
  float tana2 = tanf(alpha * 0.5f);
  LitConsts L;
  L.c = (float)M_PI / (float)NN / sina / 4.0f;
  L.q = ((float)M_PI / (float)NN) * (tana2 * 0.25f);
  L.scale = sqrtf(L.c / (float)M_PI);
  L.pe = -(1.0f - a) * (float)M_PI * 0.25f;
  return L;
}

__device__ __forceinline__ float xload(const float* __restrict__ x, uint idx, uint cap) {
  return (idx < cap) ? x[idx] : 0.f;
}

// convert 32 f32 (8x f32x4) -> 32 f16 and write to LDS row segment
__device__ __forceinline__ void cvt_write(_Float16* dst, const f32x4 pf[8]) {
#pragma unroll
  for (int q = 0; q < 4; ++q) {
    half8 h;
#pragma unroll
    for (int e = 0; e < 4; ++e) { h[e] = (_Float16)pf[2*q][e]; h[e+4] = (_Float16)pf[2*q+1][e]; }
    *(half8*)(dst + q*8) = h;
  }
}

// ---- stage 1: sinc interp GEMM, LDS-staged, xiT[b][s] f16 out ----
__global__ __launch_bounds__(256, 2) void s1_stage(const float* __restrict__ x,
                                                   _Float16* __restrict__ xiT) {
  __shared__ __align__(16) _Float16 U[2][64][UST];
  __shared__ __align__(16) float red[2][64][RST];
  const int tid = threadIdx.x;
  const int wave = tid >> 6, lane = tid & 63;
  const int l15 = lane & 15, lhi = lane >> 4;
  const int id = blockIdx.x, xcd = id & 7;
  const int b0 = (xcd >> 1) * 64;                      // same-b blocks -> same XCD pair
  const int s0 = ((xcd & 1) | ((id >> 3) << 1)) * 64;
  const int wq = wave * 32;
  const int srow = tid >> 2, scol = (tid & 3) * 32;
  const float C2PI = 0.63661977236758134f;

  f32x4 acc[4][4] = {};
  f32x4 pf[8];

  { // prologue: chunk 0
    const float* p = x + (size_t)(b0 + srow) * NN + scol;
#pragma unroll
    for (int q = 0; q < 8; ++q) pf[q] = ((const f32x4*)p)[q];
    cvt_write(&U[0][srow][scol], pf);
  }

  for (int ch = 0; ch < 32; ++ch) {
    __syncthreads();
    const int cb = ch & 1;
    if (ch < 31) {                                      // issue next chunk early
      const float* p = x + (size_t)(b0 + srow) * NN + (ch + 1) * CHW + scol;
#pragma unroll
      for (int q = 0; q < 8; ++q) pf[q] = ((const f32x4*)p)[q];
    }
    const int ibase = ch * CHW + wq + lhi * 8;
    half8 af[4];
#pragma unroll
    for (int fm = 0; fm < 4; ++fm)
      af[fm] = *(const half8*)&U[cb][fm*16 + l15][wq + lhi*8];
#pragma unroll
    for (int fn = 0; fn < 4; ++fn) {
      const int t0 = (s0 + fn*16 + l15) - ibase;
      half8 bh;
#pragma unroll
      for (int e = 0; e < 8; ++e) {
        const int t = t0 - e;
        const float sgn = (t & 1) ? -C2PI : C2PI;
        bh[e] = (_Float16)__fdividef(sgn, (float)(2*t + 1));
      }
#pragma unroll
      for (int fm = 0; fm < 4; ++fm)
        acc[fm][fn] = __builtin_amdgcn_mfma_f32_16x16x32_f16(af[fm], bh, acc[fm][fn], 0, 0, 0);
    }
    if (ch < 31) cvt_write(&U[cb ^ 1][srow][scol], pf); // late write (T14)
  }

  // 2-phase reduce of the 4 k-quarter partials
  __syncthreads();
  if (wave < 2) {
#pragma unroll
    for (int fm = 0; fm < 4; ++fm)
#pragma unroll
      for (int fn = 0; fn < 4; ++fn)
#pragma unroll
        for (int rr = 0; rr < 4; ++rr)
          red[wave][fm*16 + lhi*4 + rr][fn*16 + l15] = acc[fm][fn][rr];
  }
  __syncthreads();
  if (wave >= 2) {
#pragma unroll
    for (int fm = 0; fm < 4; ++fm)
#pragma unroll
      for (int fn = 0; fn < 4; ++fn)
#pragma unroll
        for (int rr = 0; rr < 4; ++rr)
          red[wave-2][fm*16 + lhi*4 + rr][fn*16 + l15] += acc[fm][fn][rr];
  }
  __syncthreads();

  const int frow = tid >> 2, fc0 = (tid & 3) * 16;
#pragma unroll
  for (int g = 0; g < 2; ++g) {
    half8 h;
#pragma unroll
    for (int e = 0; e < 8; ++e) {
      const int c = fc0 + g*8 + e;
      h[e] = (_Float16)(red[0][frow][c] + red[1][frow][c]);
    }
    *(half8*)(xiT + (size_t)(b0 + frow) * NN + s0 + fc0 + g*8) = h;
  }
}

// ---- stage 2: fused even+odd chirp GEMM, LDS-staged, f32 out ----
__global__ __launch_bounds__(256, 2) void s2_stage(const float* __restrict__ x,
                                                   const _Float16* __restrict__ xiT,
                                                   const float* __restrict__ order,
                                                   float* __restrict__ out) {
  __shared__ __align__(16) _Float16 U[2][64][UST];
  __shared__ __align__(16) float red[2][64][RST];
  const int tid = threadIdx.x;
  const int wave = tid >> 6, lane = tid & 63;
  const int l15 = lane & 15, lhi = lane >> 4;
  const int id = blockIdx.x, xcd = id & 7;
  const int b0 = (xcd >> 1) * 64;
  const int j0 = ((xcd & 1) | ((id >> 3) << 1)) * 64;
  const int wq = wave * 32;
  const int srow = tid >> 2, scol = (tid & 3) * 32;

  const LitConsts L = get_lit(order);
  const float P2 = 4.f * (L.c - L.q);
  int jl[4]; float jbase[4];
#pragma unroll
  for (int fn = 0; fn < 4; ++fn) {
    jl[fn] = j0 + fn*16 + l15;
    const int n = 2*jl[fn] - (NN - 1);
    jbase[fn] = fmaf(-L.q, (float)(n*n), L.pe);
  }

  f32x4 acc[4][4] = {};
  f32x4 pf[8];
  u32x4 pfo[4];

  { // prologue: even chunk 0
    const float* p = x + (size_t)(b0 + srow) * NN + scol;
#pragma unroll
    for (int q = 0; q < 8; ++q) pf[q] = ((const f32x4*)p)[q];
    cvt_write(&U[0][srow][scol], pf);
  }

  // EVEN pass (r = 2i, A from x)
  for (int ch = 0; ch < 32; ++ch) {
    __syncthreads();
    const int cb = ch & 1;
    if (ch < 31) {
      const float* p = x + (size_t)(b0 + srow) * NN + (ch + 1) * CHW + scol;
#pragma unroll
      for (int q = 0; q < 8; ++q) pf[q] = ((const f32x4*)p)[q];
    } else {  // boundary: prefetch odd chunk 0 (xiT f16)
      const _Float16* p = xiT + (size_t)(b0 + srow) * NN + scol;
#pragma unroll
      for (int q = 0; q < 4; ++q) pfo[q] = ((const u32x4*)p)[q];
    }
    const int ibase = ch * CHW + wq + lhi * 8;
    half8 af[4];
#pragma unroll
    for (int fm = 0; fm < 4; ++fm)
      af[fm] = *(const half8*)&U[cb][fm*16 + l15][wq + lhi*8];
    const int r0 = 2 * ibase;
    const int k0 = r0 - (NN - 1);
    const float bk  = -L.q * (float)(k0*k0);
    const float qk0 =  L.q * (float)k0;
#pragma unroll
    for (int fn = 0; fn < 4; ++fn) {
      const int d0 = 2*jl[fn] - r0;
      const float P0 = fmaf(L.c, (float)(d0*d0), jbase[fn] + bk);
      const float P1 = -4.f * fmaf(L.c, (float)d0, qk0);
      half8 bh;
#pragma unroll
      for (int e = 0; e < 8; ++e) {
        const float ef = (float)e;
        bh[e] = (_Float16)__cosf(fmaf(ef, fmaf(ef, P2, P1), P0));
      }
#pragma unroll
      for (int fm = 0; fm < 4; ++fm)
        acc[fm][fn] = __builtin_amdgcn_mfma_f32_16x16x32_f16(af[fm], bh, acc[fm][fn], 0, 0, 0);
    }
    if (ch < 31) cvt_write(&U[cb ^ 1][srow][scol], pf);
    else {
#pragma unroll
      for (int q = 0; q < 4; ++q) *(u32x4*)&U[cb ^ 1][srow][scol + q*8] = pfo[q];
    }
  }

  // ODD pass (r = 2i+1, A from xiT)
  for (int ch = 0; ch < 32; ++ch) {
    __syncthreads();
    const int cb = ch & 1;
    if (ch < 31) {
      const _Float16* p = xiT + (size_t)(b0 + srow) * NN + (ch + 1) * CHW + scol;
#pragma unroll
      for (int q = 0; q < 4; ++q) pfo[q] = ((const u32x4*)p)[q];
    }
    const int ibase = ch * CHW + wq + lhi * 8;
    half8 af[4];
#pragma unroll
    for (int fm = 0; fm < 4; ++fm)
      af[fm] = *(const half8*)&U[cb][fm*16 + l15][wq + lhi*8];
    const int r0 = 2 * ibase + 1;
    const int k0 = r0 - (NN - 1);
    const float bk  = -L.q * (float)(k0*k0);
    const float qk0 =  L.q * (float)k0;
#pragma unroll
    for (int fn = 0; fn < 4; ++fn) {
      const int d0 = 2*jl[fn] - r0;
      const float P0 = fmaf(L.c, (float)(d0*d0), jbase[fn] + bk);
      const float P1 = -4.f * fmaf(L.c, (float)d0, qk0);
      half8 bh;
#pragma unroll
      for (int e = 0; e < 8; ++e) {
        const float ef = (float)e;
        float w = __cosf(fmaf(ef, fmaf(ef, P2, P1), P0));
        if (ibase + e > NN - 2) w = 0.f;   // r=8191 pad does not exist
        bh[e] = (_Float16)w;
      }
#pragma unroll
      for (int fm = 0; fm < 4; ++fm)
        acc[fm][fn] = __builtin_amdgcn_mfma_f32_16x16x32_f16(af[fm], bh, acc[fm][fn], 0, 0, 0);
    }
    if (ch < 31) {
#pragma unroll
      for (int q = 0; q < 4; ++q) *(u32x4*)&U[cb ^ 1][srow][scol + q*8] = pfo[q];
    }
  }

  // 2-phase reduce + scaled coalesced store
  __syncthreads();
  if (wave < 2) {
#pragma unroll
    for (int fm = 0; fm < 4; ++fm)
#pragma unroll
      for (int fn = 0; fn < 4; ++fn)
#pragma unroll
        for (int rr = 0; rr < 4; ++rr)
          red[wave][fm*16 + lhi*4 + rr][fn*16 + l15] = acc[fm][fn][rr];
  }
  __syncthreads();
  if (wave >= 2) {
#pragma unroll
    for (int fm = 0; fm < 4; ++fm)
#pragma unroll
      for (int fn = 0; fn < 4; ++fn)
#pragma unroll
        for (int rr = 0; rr < 4; ++rr)
          red[wave-2][fm*16 + lhi*4 + rr][fn*16 + l15] += acc[fm][fn][rr];
  }
  __syncthreads();

  const int frow = tid >> 2, fc0 = (tid & 3) * 16;
#pragma unroll
  for (int g = 0; g < 4; ++g) {
    f32x4 a = *(const f32x4*)&red[0][frow][fc0 + g*4];
    f32x4 b = *(const f32x4*)&red[1][frow][fc0 + g*4];
    f32x4 v;
#pragma unroll
    for (int e = 0; e < 4; ++e) v[e] = L.scale * (a[e] + b[e]);
    *(f32x4*)(out + (size_t)(b0 + frow) * NN + j0 + fc0 + g*4) = v;
  }
}

// ======================= R13 proven fallback (small ws) =======================

__global__ __launch_bounds__(256) void frft_interp(const float* __restrict__ x,
                                                   __half* __restrict__ xi,
                                                   int b_lo, int cnt,
                                                   uint xi_cap, uint x_cap) {
  __shared__ __align__(16) float wt1[32][64];
  __shared__ __align__(16) float xt[32][64];
  const int tid = threadIdx.x;
  const int s0 = blockIdx.x * 64, cb0 = blockIdx.y * 64;
  const int tx = tid & 15, ty = tid >> 4;
  const int ss0 = ty * 4, bb0 = tx * 4;

  float acc[4][4] = {};
  for (int i0 = 0; i0 < NN; i0 += 32) {
#pragma unroll
    for (int e = 0; e < 8; ++e) {
      int idx = tid + e * 256, qq = idx >> 6, ss = idx & 63;
      int t = s0 + ss - (i0 + qq);
      float sgn = (t & 1) ? -0.63661977236758134f : 0.63661977236758134f;
      wt1[qq][ss] = __fdividef(sgn, (float)(2 * t + 1));
    }
#pragma unroll
    for (int e = 0; e < 8; ++e) {
      int idx = tid + e * 256, qq = idx >> 6, bb = idx & 63;
      xt[qq][bb] = xload(x, (uint)(b_lo + cb0 + bb) * NN + (i0 + qq), x_cap);
    }
    __syncthreads();
#pragma unroll
    for (int qq = 0; qq < 32; ++qq) {
      float4 wv = *(const float4*)&wt1[qq][ss0];
      float4 uv = *(const float4*)&xt[qq][bb0];
      float w[4] = {wv.x, wv.y, wv.z, wv.w};
      float u[4] = {uv.x, uv.y, uv.z, uv.w};
#pragma unroll
      for (int aa = 0; aa < 4; ++aa)
#pragma unroll
        for (int cc = 0; cc < 4; ++cc) acc[aa][cc] = fmaf(w[aa], u[cc], acc[aa][cc]);
    }
    __syncthreads();
  }
#pragma unroll
  for (int aa = 0; aa < 4; ++aa) {
    int s = s0 + ss0 + aa;
    if (s < NN - 1) {
#pragma unroll
      for (int cc = 0; cc < 4; ++cc) {
        int cb = cb0 + bb0 + cc;
        if (cb < cnt) {
          uint o = (uint)s * (uint)cnt + (uint)cb;
          if (o < xi_cap) xi[o] = __float2half(acc[aa][cc]);
        }
      }
    }
  }
}

#define TJ 32
#define TB 64
#define TK 32
__global__ __launch_bounds__(256) void frft_gemm(const float* __restrict__ x,
                                                 const __half* __restrict__ xi,
                                                 const float* __restrict__ order,
                                                 float* __restrict__ out,
                                                 int b_lo, int cnt,
                                                 uint xi_cap, uint x_cap,
                                                 uint out_capf) {
  __shared__ __align__(16) float wt[TK][TJ];
  __shared__ __align__(16) float ut[TK][TB];
  const int tid = threadIdx.x;
  const int j0 = blockIdx.x * TJ, cb0 = blockIdx.y * TB;
  const int tx = tid & 15, ty = tid >> 4;
  const int jj0 = ty * 2, bb0 = tx * 4;

  LitConsts L = get_lit(order);
  float acc[2][4] = {};

  for (int r0 = 0; r0 < KK; r0 += TK) {
#pragma unroll
    for (int e = 0; e < 4; ++e) {
      int idx = tid + e * 256, qq = idx >> 5, jj = idx & 31;
      int r = r0 + qq;
      float wv = 0.f;
      if (r < KK) {
        int j = j0 + jj;
        int n = 2 * j - (NN - 1);
        int d = 2 * j - r;
        int k = r - (NN - 1);
        float base = fmaf(-L.q, (float)(n * n), L.pe);
        float ph = fmaf(L.c, (float)(d * d), fmaf(-L.q, (float)(k * k), base));
        wv = __cosf(ph);
      }
      wt[qq][jj] = wv;
    }
#pragma unroll
    for (int e = 0; e < 8; ++e) {
      int idx = tid + e * 256, qq = idx >> 6, bb = idx & 63;
      int r = r0 + qq, cb = cb0 + bb;
      float v = 0.f;
      if (r < KK && cb < cnt) {
        if (r & 1) {
          uint o = (uint)(r >> 1) * (uint)cnt + (uint)cb;
          v = (o < xi_cap) ? __half2float(xi[o]) : 0.f;
        } else {
          v = xload(x, (uint)(b_lo + cb) * NN + (uint)(r >> 1), x_cap);
        }
      }
      ut[qq][bb] = v;
    }
    __syncthreads();
#pragma unroll
    for (int qq = 0; qq < TK; ++qq) {
      float2 wv = *(const float2*)&wt[qq][jj0];
      float4 uv = *(const float4*)&ut[qq][bb0];
      float w[2] = {wv.x, wv.y};
      float u[4] = {uv.x, uv.y, uv.z, uv.w};
#pragma unroll
      for (int aa = 0; aa < 2; ++aa)
#pragma unroll
        for (int cc = 0; cc < 4; ++cc)
          acc[aa][cc] = fmaf(w[aa], u[cc], acc[aa][cc]);
    }
    __syncthreads();
  }

#pragma unroll
  for (int aa = 0; aa < 2; ++aa) {
    int j = j0 + jj0 + aa;
#pragma unroll
    for (int cc = 0; cc < 4; ++cc) {
      int cb = cb0 + bb0 + cc;
      if (cb < cnt) {
        uint idx = (uint)(b_lo + cb) * NN + (uint)j;
        if (idx < out_capf) out[idx] = L.scale * acc[aa][cc];
      }
    }
  }
}

__global__ __launch_bounds__(256) void frft_gemm1(const float* __restrict__ x,
                                                  const float* __restrict__ order,
                                                  float* __restrict__ out,
                                                  uint x_cap, uint out_capf) {
  __shared__ float xrow[NN];
  __shared__ float xio[NN - 1];
  __shared__ float red[4][64];
  const int tid = threadIdx.x;
  const int j0 = blockIdx.x * 64;
  LitConsts L = get_lit(order);

#pragma unroll
  for (int e = 0; e < 16; ++e) {
    int i = tid + e * 256;
    xrow[i] = xload(x, (uint)255 * NN + (uint)i, x_cap);
  }
  __syncthreads();
#pragma unroll
  for (int m = 0; m < 16; ++m) {
    int s = tid + m * 256;
    if (s < NN - 1) {
      float a0 = 0.f;
      for (int i = 0; i < NN; ++i) {
        int t = s - i;
        float sgn = (t & 1) ? -0.63661977236758134f : 0.63661977236758134f;
        a0 = fmaf(xrow[i], __fdividef(sgn, (float)(2 * t + 1)), a0);
      }
      xio[s] = a0;
    }
  }
  __syncthreads();

  const int ty = tid >> 6, jj = tid & 63;
  const int j = j0 + jj;
  const int n = 2 * j - (NN - 1);
  const float base = fmaf(-L.q, (float)(n * n), L.pe);
  float acc = 0.f;
  int rend = (ty + 1) * 2048; if (rend > KK) rend = KK;
  for (int r = ty * 2048; r < rend; ++r) {
    int d = 2 * j - r;
    int k = r - (NN - 1);
    float ph = fmaf(L.c, (float)(d * d), fmaf(-L.q, (float)(k * k), base));
    float u = (r & 1) ? xio[r >> 1] : xrow[r >> 1];
    acc = fmaf(__cosf(ph), u, acc);
  }
  red[ty][jj] = acc;
  __syncthreads();
  if (ty == 0) {
    float t = red[0][jj] + red[1][jj] + red[2][jj] + red[3][jj];
    uint idx = (uint)255 * NN + (uint)j;
    if (idx < out_capf) out[idx] = L.scale * t;
  }
}

extern "C" void kernel_launch(void* const* d_in, const int* in_sizes, int n_in,
                              void* d_out, int out_size, void* d_ws, size_t ws_size,
                              hipStream_t stream) {
  const float* x     = (const float*)d_in[0];
  const float* order = (const float*)d_in[1];
  float* outf = (float*)d_out;
  const uint x_cap    = (uint)in_sizes[0];
  const uint out_capf = (uint)out_size;
  const size_t ws_halves = ws_size / 2;

  // ---- R17 LDS-staged MFMA path ----
  if (ws_size >= (size_t)NN * BB * 2 &&
      out_capf >= (uint)NN * BB && x_cap >= (uint)NN * BB) {
    _Float16* xiT = (_Float16*)d_ws;
    s1_stage<<<dim3(256), 256, 0, stream>>>(x, xiT);
    s2_stage<<<dim3(256), 256, 0, stream>>>(x, xiT, order, outf);
    return;
  }

  // ---- R13 proven fallback paths ----
  if (ws_halves >= (size_t)(NN - 1) * BB) {
    uint xi_cap = (uint)((size_t)(NN - 1) * BB);
    frft_interp<<<dim3(64, 4), 256, 0, stream>>>(x, (__half*)d_ws, 0, BB, xi_cap, x_cap);
    frft_gemm<<<dim3(NN / TJ, BB / TB), 256, 0, stream>>>(x, (__half*)d_ws, order, outf,
                                                          0, BB, xi_cap, x_cap, out_capf);
  } else {
    struct Chunk { int lo, cnt; };
    const Chunk ch[6] = { {0,170}, {170,57}, {227,19}, {246,6}, {252,2}, {254,1} };
    for (int i = 0; i < 6; ++i) {
      const Chunk& c = ch[i];
      uint off = (uint)(c.lo + c.cnt) * (uint)NN;
      __half* xp = (__half*)(outf + off);
      size_t need = (size_t)(NN - 1) * (size_t)c.cnt;
      size_t avail = (out_capf > off) ? (size_t)(out_capf - off) * 2 : 0;
      uint xi_cap = (uint)(need < avail ? need : avail);
      frft_interp<<<dim3(64, (unsigned)((c.cnt + 63) / 64)), 256, 0, stream>>>(
          x, xp, c.lo, c.cnt, xi_cap, x_cap);
      frft_gemm<<<dim3(NN / TJ, (unsigned)((c.cnt + TB - 1) / TB)), 256, 0, stream>>>(
          x, xp, order, outf, c.lo, c.cnt, xi_cap, x_cap, out_capf);
    }
    if (ws_halves >= (size_t)(NN - 1)) {
      uint xi_cap = (uint)(NN - 1);
      frft_interp<<<dim3(64, 1), 256, 0, stream>>>(x, (__half*)d_ws, 255, 1, xi_cap, x_cap);
      frft_gemm<<<dim3(NN / TJ, 1), 256, 0, stream>>>(x, (__half*)d_ws, order, outf,
                                                      255, 1, xi_cap, x_cap, out_capf);
    } else {
      frft_gemm1<<<64, 256, 0, stream>>>(x, order, outf, x_cap, out_capf);
    }
  }
}

// Round 5
// 156.193 us; speedup vs baseline: 1.5576x; 1.2081x over previous
//
#include <hip/hip_runtime.h>
#include <hip/hip_fp16.h>
#include <math.h>

// FrFT (Ozaktas, 0.5<a<1.5): x[256,4096] f32, order f32 -> Re(complex64) f32
// out[b*4096+j]. R18: fix R17's two measured diseases:
//   (1) 1.57M LDS bank conflicts (UST=136 pad => 68 dw ==4 mod 32): replace
//       row-major padded tile with FRAGMENT-MAJOR XOR layout
//       U[buf][slot][row][8] halves, slot = colgrp ^ (row&7) -- write and
//       read both hit the b128 bank floor by construction.
//   (2) 1 wave/SIMD (grid 256 x 4 waves): now 8 waves/block (512 thr),
//       wave = (kq = w&3) x (fn-half = w>>2), fm=4 x fn=2 per wave ->
//       2 waves/SIMD, cos/weight count unchanged (2 per MFMA).
// Reduce: 4 k-quarter partials via red[2] LDS planes (no atomics).
// Weight math identical to proven R14-R17 (quadratic phase, __cosf,
// __fdividef); odd pad r=8191 weight-zeroed.

#define NN 4096
#define BB 256
#define KK (2*NN - 1)
#define CHW 128

typedef unsigned int uint;
typedef __attribute__((ext_vector_type(4))) float f32x4;
typedef __attribute__((ext_vector_type(4))) uint u32x4;
typedef __attribute__((ext_vector_type(8))) _Float16 half8;

struct LitConsts { float c, q, scale, pe; };

__device__ __forceinline__ LitConsts get_lit(const float* order) {
  float a = order[0];
  float alpha = a * (float)M_PI * 0.5f;
  float sina = sinf(alpha);
  float tana2 = tanf(alpha * 0.5f);
  LitConsts L;
  L.c = (float)M_PI / (float)NN / sina / 4.0f;
  L.q = ((float)M_PI / (float)NN) * (tana2 * 0.25f);
  L.scale = sqrtf(L.c / (float)M_PI);
  L.pe = -(1.0f - a) * (float)M_PI * 0.25f;
  return L;
}

__device__ __forceinline__ float xload(const float* __restrict__ x, uint idx, uint cap) {
  return (idx < cap) ? x[idx] : 0.f;
}

// stage 16 f32 (4x f32x4) as 16 halves into two XOR slots of U[buf]
__device__ __forceinline__ void stage_f32(_Float16 (*Ub)[64][8], int scg, int srow,
                                          const f32x4 pf[4]) {
  const int xr = srow & 7;
  half8 h0, h1;
#pragma unroll
  for (int e = 0; e < 4; ++e) {
    h0[e] = (_Float16)pf[0][e]; h0[e + 4] = (_Float16)pf[1][e];
    h1[e] = (_Float16)pf[2][e]; h1[e + 4] = (_Float16)pf[3][e];
  }
  *(half8*)Ub[scg ^ xr][srow] = h0;
  *(half8*)Ub[(scg + 1) ^ xr][srow] = h1;
}

__device__ __forceinline__ void stage_f16(_Float16 (*Ub)[64][8], int scg, int srow,
                                          const u32x4 ph[2]) {
  const int xr = srow & 7;
  *(u32x4*)Ub[scg ^ xr][srow] = ph[0];
  *(u32x4*)Ub[(scg + 1) ^ xr][srow] = ph[1];
}

// ---- stage 1: sinc interp GEMM; 256 blocks x 512 thr; tile 64b x 64s ----
__global__ __launch_bounds__(512, 2) void s1_v2(const float* __restrict__ x,
                                                _Float16* __restrict__ xiT) {
  __shared__ __align__(16) _Float16 U[2][16][64][8];  // 32 KB
  __shared__ __align__(16) float red[2][64][68];      // 34.8 KB
  const int tid = threadIdx.x;
  const int w = tid >> 6, lane = tid & 63;
  const int l15 = lane & 15, lhi = lane >> 4;
  const int kq = w & 3, fh = w >> 2;
  const int id = blockIdx.x, xcd = id & 7;
  const int b0 = (xcd >> 1) * 64;                     // same-b blocks -> XCD pair
  const int s0 = ((xcd & 1) | ((id >> 3) << 1)) * 64;
  const int srow = tid >> 3;                          // 0..63
  const int scg = (tid & 7) * 2;                      // col-group pair
  const int xr = l15 & 7;
  const float C2PI = 0.63661977236758134f;

  f32x4 acc[4][2] = {};
  f32x4 pf[4];

  { // prologue: stage chunk 0
    const float* p = x + (size_t)(b0 + srow) * NN + scg * 8;
#pragma unroll
    for (int q = 0; q < 4; ++q) pf[q] = ((const f32x4*)p)[q];
    stage_f32(U[0], scg, srow, pf);
  }

  for (int ch = 0; ch < 32; ++ch) {
    __syncthreads();
    const int cb = ch & 1;
    if (ch < 31) {
      const float* p = x + (size_t)(b0 + srow) * NN + (ch + 1) * CHW + scg * 8;
#pragma unroll
      for (int q = 0; q < 4; ++q) pf[q] = ((const f32x4*)p)[q];
    }
    half8 af[4];
#pragma unroll
    for (int fm = 0; fm < 4; ++fm)
      af[fm] = *(const half8*)U[cb][(kq * 4 + lhi) ^ xr][fm * 16 + l15];
    const int i0 = ch * CHW + kq * 32 + lhi * 8;
#pragma unroll
    for (int g = 0; g < 2; ++g) {
      const int t0 = (s0 + (fh * 2 + g) * 16 + l15) - i0;
      half8 bh;
#pragma unroll
      for (int e = 0; e < 8; ++e) {
        const int t = t0 - e;
        const float sgn = (t & 1) ? -C2PI : C2PI;
        bh[e] = (_Float16)__fdividef(sgn, (float)(2 * t + 1));
      }
#pragma unroll
      for (int fm = 0; fm < 4; ++fm)
        acc[fm][g] = __builtin_amdgcn_mfma_f32_16x16x32_f16(af[fm], bh, acc[fm][g], 0, 0, 0);
    }
    if (ch < 31) stage_f32(U[cb ^ 1], scg, srow, pf);
  }

  // k-quarter reduce: kq 0,1 write planes; kq 2,3 add; then sum+store
  __syncthreads();
  if (kq < 2) {
#pragma unroll
    for (int fm = 0; fm < 4; ++fm)
#pragma unroll
      for (int g = 0; g < 2; ++g)
#pragma unroll
        for (int rr = 0; rr < 4; ++rr)
          red[kq][fm * 16 + lhi * 4 + rr][(fh * 2 + g) * 16 + l15] = acc[fm][g][rr];
  }
  __syncthreads();
  if (kq >= 2) {
#pragma unroll
    for (int fm = 0; fm < 4; ++fm)
#pragma unroll
      for (int g = 0; g < 2; ++g)
#pragma unroll
        for (int rr = 0; rr < 4; ++rr)
          red[kq - 2][fm * 16 + lhi * 4 + rr][(fh * 2 + g) * 16 + l15] += acc[fm][g][rr];
  }
  __syncthreads();

  const int col0 = (tid & 7) * 8;
  half8 h;
#pragma unroll
  for (int e = 0; e < 8; ++e)
    h[e] = (_Float16)(red[0][srow][col0 + e] + red[1][srow][col0 + e]);
  *(half8*)(xiT + (size_t)(b0 + srow) * NN + s0 + col0) = h;
}

// ---- stage 2: fused even+odd chirp GEMM; 256 blocks x 512 thr ----
__global__ __launch_bounds__(512, 2) void s2_v2(const float* __restrict__ x,
                                                const _Float16* __restrict__ xiT,
                                                const float* __restrict__ order,
                                                float* __restrict__ out) {
  __shared__ __align__(16) _Float16 U[2][16][64][8];
  __shared__ __align__(16) float red[2][64][68];
  const int tid = threadIdx.x;
  const int w = tid >> 6, lane = tid & 63;
  const int l15 = lane & 15, lhi = lane >> 4;
  const int kq = w & 3, fh = w >> 2;
  const int id = blockIdx.x, xcd = id & 7;
  const int b0 = (xcd >> 1) * 64;
  const int j0 = ((xcd & 1) | ((id >> 3) << 1)) * 64;
  const int srow = tid >> 3;
  const int scg = (tid & 7) * 2;
  const int xr = l15 & 7;

  const LitConsts L = get_lit(order);
  const float P2 = 4.f * (L.c - L.q);
  int jl[2]; float jbase[2];
#pragma unroll
  for (int g = 0; g < 2; ++g) {
    jl[g] = j0 + (fh * 2 + g) * 16 + l15;
    const int n = 2 * jl[g] - (NN - 1);
    jbase[g] = fmaf(-L.q, (float)(n * n), L.pe);
  }

  f32x4 acc[4][2] = {};
  f32x4 pf[4];
  u32x4 ph2[2];

  { // prologue: stage even chunk 0
    const float* p = x + (size_t)(b0 + srow) * NN + scg * 8;
#pragma unroll
    for (int q = 0; q < 4; ++q) pf[q] = ((const f32x4*)p)[q];
    stage_f32(U[0], scg, srow, pf);
  }

  // EVEN pass (r = 2i, A from x)
  for (int ch = 0; ch < 32; ++ch) {
    __syncthreads();
    const int cb = ch & 1;
    if (ch < 31) {
      const float* p = x + (size_t)(b0 + srow) * NN + (ch + 1) * CHW + scg * 8;
#pragma unroll
      for (int q = 0; q < 4; ++q) pf[q] = ((const f32x4*)p)[q];
    } else {  // boundary: prefetch odd chunk 0 from xiT
      const _Float16* p = xiT + (size_t)(b0 + srow) * NN + scg * 8;
      ph2[0] = ((const u32x4*)p)[0];
      ph2[1] = ((const u32x4*)p)[1];
    }
    half8 af[4];
#pragma unroll
    for (int fm = 0; fm < 4; ++fm)
      af[fm] = *(const half8*)U[cb][(kq * 4 + lhi) ^ xr][fm * 16 + l15];
    const int i0 = ch * CHW + kq * 32 + lhi * 8;
    const int r0 = 2 * i0;
    const int k0 = r0 - (NN - 1);
    const float bk  = -L.q * (float)(k0 * k0);
    const float qk0 =  L.q * (float)k0;
#pragma unroll
    for (int g = 0; g < 2; ++g) {
      const int d0 = 2 * jl[g] - r0;
      const float P0 = fmaf(L.c, (float)(d0 * d0), jbase[g] + bk);
      const float P1 = -4.f * fmaf(L.c, (float)d0, qk0);
      half8 bh;
#pragma unroll
      for (int e = 0; e < 8; ++e) {
        const float ef = (float)e;
        bh[e] = (_Float16)__cosf(fmaf(ef, fmaf(ef, P2, P1), P0));
      }
#pragma unroll
      for (int fm = 0; fm < 4; ++fm)
        acc[fm][g] = __builtin_amdgcn_mfma_f32_16x16x32_f16(af[fm], bh, acc[fm][g], 0, 0, 0);
    }
    if (ch < 31) stage_f32(U[cb ^ 1], scg, srow, pf);
    else         stage_f16(U[cb ^ 1], scg, srow, ph2);
  }

  // ODD pass (r = 2i+1, A from xiT)
  for (int ch = 0; ch < 32; ++ch) {
    __syncthreads();
    const int cb = ch & 1;
    if (ch < 31) {
      const _Float16* p = xiT + (size_t)(b0 + srow) * NN + (ch + 1) * CHW + scg * 8;
      ph2[0] = ((const u32x4*)p)[0];
      ph2[1] = ((const u32x4*)p)[1];
    }
    half8 af[4];
#pragma unroll
    for (int fm = 0; fm < 4; ++fm)
      af[fm] = *(const half8*)U[cb][(kq * 4 + lhi) ^ xr][fm * 16 + l15];
    const int i0 = ch * CHW + kq * 32 + lhi * 8;
    const int r0 = 2 * i0 + 1;
    const int k0 = r0 - (NN - 1);
    const float bk  = -L.q * (float)(k0 * k0);
    const float qk0 =  L.q * (float)k0;
#pragma unroll
    for (int g = 0; g < 2; ++g) {
      const int d0 = 2 * jl[g] - r0;
      const float P0 = fmaf(L.c, (float)(d0 * d0), jbase[g] + bk);
      const float P1 = -4.f * fmaf(L.c, (float)d0, qk0);
      half8 bh;
#pragma unroll
      for (int e = 0; e < 8; ++e) {
        const float ef = (float)e;
        float wv = __cosf(fmaf(ef, fmaf(ef, P2, P1), P0));
        if (i0 + e > NN - 2) wv = 0.f;   // r=8191 pad does not exist
        bh[e] = (_Float16)wv;
      }
#pragma unroll
      for (int fm = 0; fm < 4; ++fm)
        acc[fm][g] = __builtin_amdgcn_mfma_f32_16x16x32_f16(af[fm], bh, acc[fm][g], 0, 0, 0);
    }
    if (ch < 31) stage_f16(U[cb ^ 1], scg, srow, ph2);
  }

  // k-quarter reduce + scaled store
  __syncthreads();
  if (kq < 2) {
#pragma unroll
    for (int fm = 0; fm < 4; ++fm)
#pragma unroll
      for (int g = 0; g < 2; ++g)
#pragma unroll
        for (int rr = 0; rr < 4; ++rr)
          red[kq][fm * 16 + lhi * 4 + rr][(fh * 2 + g) * 16 + l15] = acc[fm][g][rr];
  }
  __syncthreads();
  if (kq >= 2) {
#pragma unroll
    for (int fm = 0; fm < 4; ++fm)
#pragma unroll
      for (int g = 0; g < 2; ++g)
#pragma unroll
        for (int rr = 0; rr < 4; ++rr)
          red[kq - 2][fm * 16 + lhi * 4 + rr][(fh * 2 + g) * 16 + l15] += acc[fm][g][rr];
  }
  __syncthreads();

  const int col0 = (tid & 7) * 8;
#pragma unroll
  for (int g = 0; g < 2; ++g) {
    f32x4 v;
#pragma unroll
    for (int e = 0; e < 4; ++e)
      v[e] = L.scale * (red[0][srow][col0 + g * 4 + e] + red[1][srow][col0 + g * 4 + e]);
    *(f32x4*)(out + (size_t)(b0 + srow) * NN + j0 + col0 + g * 4) = v;
  }
}

// ======================= R13 proven fallback (small ws) =======================

__global__ __launch_bounds__(256) void frft_interp(const float* __restrict__ x,
                                                   __half* __restrict__ xi,
                                                   int b_lo, int cnt,
                                                   uint xi_cap, uint x_cap) {
  __shared__ __align__(16) float wt1[32][64];
  __shared__ __align__(16) float xt[32][64];
  const int tid = threadIdx.x;
  const int s0 = blockIdx.x * 64, cb0 = blockIdx.y * 64;
  const int tx = tid & 15, ty = tid >> 4;
  const int ss0 = ty * 4, bb0 = tx * 4;

  float acc[4][4] = {};
  for (int i0 = 0; i0 < NN; i0 += 32) {
#pragma unroll
    for (int e = 0; e < 8; ++e) {
      int idx = tid + e * 256, qq = idx >> 6, ss = idx & 63;
      int t = s0 + ss - (i0 + qq);
      float sgn = (t & 1) ? -0.63661977236758134f : 0.63661977236758134f;
      wt1[qq][ss] = __fdividef(sgn, (float)(2 * t + 1));
    }
#pragma unroll
    for (int e = 0; e < 8; ++e) {
      int idx = tid + e * 256, qq = idx >> 6, bb = idx & 63;
      xt[qq][bb] = xload(x, (uint)(b_lo + cb0 + bb) * NN + (i0 + qq), x_cap);
    }
    __syncthreads();
#pragma unroll
    for (int qq = 0; qq < 32; ++qq) {
      float4 wv = *(const float4*)&wt1[qq][ss0];
      float4 uv = *(const float4*)&xt[qq][bb0];
      float w[4] = {wv.x, wv.y, wv.z, wv.w};
      float u[4] = {uv.x, uv.y, uv.z, uv.w};
#pragma unroll
      for (int aa = 0; aa < 4; ++aa)
#pragma unroll
        for (int cc = 0; cc < 4; ++cc) acc[aa][cc] = fmaf(w[aa], u[cc], acc[aa][cc]);
    }
    __syncthreads();
  }
#pragma unroll
  for (int aa = 0; aa < 4; ++aa) {
    int s = s0 + ss0 + aa;
    if (s < NN - 1) {
#pragma unroll
      for (int cc = 0; cc < 4; ++cc) {
        int cb = cb0 + bb0 + cc;
        if (cb < cnt) {
          uint o = (uint)s * (uint)cnt + (uint)cb;
          if (o < xi_cap) xi[o] = __float2half(acc[aa][cc]);
        }
      }
    }
  }
}

#define TJ 32
#define TB 64
#define TK 32
__global__ __launch_bounds__(256) void frft_gemm(const float* __restrict__ x,
                                                 const __half* __restrict__ xi,
                                                 const float* __restrict__ order,
                                                 float* __restrict__ out,
                                                 int b_lo, int cnt,
                                                 uint xi_cap, uint x_cap,
                                                 uint out_capf) {
  __shared__ __align__(16) float wt[TK][TJ];
  __shared__ __align__(16) float ut[TK][TB];
  const int tid = threadIdx.x;
  const int j0 = blockIdx.x * TJ, cb0 = blockIdx.y * TB;
  const int tx = tid & 15, ty = tid >> 4;
  const int jj0 = ty * 2, bb0 = tx * 4;

  LitConsts L = get_lit(order);
  float acc[2][4] = {};

  for (int r0 = 0; r0 < KK; r0 += TK) {
#pragma unroll
    for (int e = 0; e < 4; ++e) {
      int idx = tid + e * 256, qq = idx >> 5, jj = idx & 31;
      int r = r0 + qq;
      float wv = 0.f;
      if (r < KK) {
        int j = j0 + jj;
        int n = 2 * j - (NN - 1);
        int d = 2 * j - r;
        int k = r - (NN - 1);
        float base = fmaf(-L.q, (float)(n * n), L.pe);
        float ph = fmaf(L.c, (float)(d * d), fmaf(-L.q, (float)(k * k), base));
        wv = __cosf(ph);
      }
      wt[qq][jj] = wv;
    }
#pragma unroll
    for (int e = 0; e < 8; ++e) {
      int idx = tid + e * 256, qq = idx >> 6, bb = idx & 63;
      int r = r0 + qq, cb = cb0 + bb;
      float v = 0.f;
      if (r < KK && cb < cnt) {
        if (r & 1) {
          uint o = (uint)(r >> 1) * (uint)cnt + (uint)cb;
          v = (o < xi_cap) ? __half2float(xi[o]) : 0.f;
        } else {
          v = xload(x, (uint)(b_lo + cb) * NN + (uint)(r >> 1), x_cap);
        }
      }
      ut[qq][bb] = v;
    }
    __syncthreads();
#pragma unroll
    for (int qq = 0; qq < TK; ++qq) {
      float2 wv = *(const float2*)&wt[qq][jj0];
      float4 uv = *(const float4*)&ut[qq][bb0];
      float w[2] = {wv.x, wv.y};
      float u[4] = {uv.x, uv.y, uv.z, uv.w};
#pragma unroll
      for (int aa = 0; aa < 2; ++aa)
#pragma unroll
        for (int cc = 0; cc < 4; ++cc)
          acc[aa][cc] = fmaf(w[aa], u[cc], acc[aa][cc]);
    }
    __syncthreads();
  }

#pragma unroll
  for (int aa = 0; aa < 2; ++aa) {
    int j = j0 + jj0 + aa;
#pragma unroll
    for (int cc = 0; cc < 4; ++cc) {
      int cb = cb0 + bb0 + cc;
      if (cb < cnt) {
        uint idx = (uint)(b_lo + cb) * NN + (uint)j;
        if (idx < out_capf) out[idx] = L.scale * acc[aa][cc];
      }
    }
  }
}

__global__ __launch_bounds__(256) void frft_gemm1(const float* __restrict__ x,
                                                  const float* __restrict__ order,
                                                  float* __restrict__ out,
                                                  uint x_cap, uint out_capf) {
  __shared__ float xrow[NN];
  __shared__ float xio[NN - 1];
  __shared__ float red[4][64];
  const int tid = threadIdx.x;
  const int j0 = blockIdx.x * 64;
  LitConsts L = get_lit(order);

#pragma unroll
  for (int e = 0; e < 16; ++e) {
    int i = tid + e * 256;
    xrow[i] = xload(x, (uint)255 * NN + (uint)i, x_cap);
  }
  __syncthreads();
#pragma unroll
  for (int m = 0; m < 16; ++m) {
    int s = tid + m * 256;
    if (s < NN - 1) {
      float a0 = 0.f;
      for (int i = 0; i < NN; ++i) {
        int t = s - i;
        float sgn = (t & 1) ? -0.63661977236758134f : 0.63661977236758134f;
        a0 = fmaf(xrow[i], __fdividef(sgn, (float)(2 * t + 1)), a0);
      }
      xio[s] = a0;
    }
  }
  __syncthreads();

  const int ty = tid >> 6, jj = tid & 63;
  const int j = j0 + jj;
  const int n = 2 * j - (NN - 1);
  const float base = fmaf(-L.q, (float)(n * n), L.pe);
  float acc = 0.f;
  int rend = (ty + 1) * 2048; if (rend > KK) rend = KK;
  for (int r = ty * 2048; r < rend; ++r) {
    int d = 2 * j - r;
    int k = r - (NN - 1);
    float ph = fmaf(L.c, (float)(d * d), fmaf(-L.q, (float)(k * k), base));
    float u = (r & 1) ? xio[r >> 1] : xrow[r >> 1];
    acc = fmaf(__cosf(ph), u, acc);
  }
  red[ty][jj] = acc;
  __syncthreads();
  if (ty == 0) {
    float t = red[0][jj] + red[1][jj] + red[2][jj] + red[3][jj];
    uint idx = (uint)255 * NN + (uint)j;
    if (idx < out_capf) out[idx] = L.scale * t;
  }
}

extern "C" void kernel_launch(void* const* d_in, const int* in_sizes, int n_in,
                              void* d_out, int out_size, void* d_ws, size_t ws_size,
                              hipStream_t stream) {
  const float* x     = (const float*)d_in[0];
  const float* order = (const float*)d_in[1];
  float* outf = (float*)d_out;
  const uint x_cap    = (uint)in_sizes[0];
  const uint out_capf = (uint)out_size;
  const size_t ws_halves = ws_size / 2;

  // ---- R18 conflict-free LDS-staged MFMA path ----
  if (ws_size >= (size_t)NN * BB * 2 &&
      out_capf >= (uint)NN * BB && x_cap >= (uint)NN * BB) {
    _Float16* xiT = (_Float16*)d_ws;
    s1_v2<<<dim3(256), 512, 0, stream>>>(x, xiT);
    s2_v2<<<dim3(256), 512, 0, stream>>>(x, xiT, order, outf);
    return;
  }

  // ---- R13 proven fallback paths ----
  if (ws_halves >= (size_t)(NN - 1) * BB) {
    uint xi_cap = (uint)((size_t)(NN - 1) * BB);
    frft_interp<<<dim3(64, 4), 256, 0, stream>>>(x, (__half*)d_ws, 0, BB, xi_cap, x_cap);
    frft_gemm<<<dim3(NN / TJ, BB / TB), 256, 0, stream>>>(x, (__half*)d_ws, order, outf,
                                                          0, BB, xi_cap, x_cap, out_capf);
  } else {
    struct Chunk { int lo, cnt; };
    const Chunk ch[6] = { {0,170}, {170,57}, {227,19}, {246,6}, {252,2}, {254,1} };
    for (int i = 0; i < 6; ++i) {
      const Chunk& c = ch[i];
      uint off = (uint)(c.lo + c.cnt) * (uint)NN;
      __half* xp = (__half*)(outf + off);
      size_t need = (size_t)(NN - 1) * (size_t)c.cnt;
      size_t avail = (out_capf > off) ? (size_t)(out_capf - off) * 2 : 0;
      uint xi_cap = (uint)(need < avail ? need : avail);
      frft_interp<<<dim3(64, (unsigned)((c.cnt + 63) / 64)), 256, 0, stream>>>(
          x, xp, c.lo, c.cnt, xi_cap, x_cap);
      frft_gemm<<<dim3(NN / TJ, (unsigned)((c.cnt + TB - 1) / TB)), 256, 0, stream>>>(
          x, xp, order, outf, c.lo, c.cnt, xi_cap, x_cap, out_capf);
    }
    if (ws_halves >= (size_t)(NN - 1)) {
      uint xi_cap = (uint)(NN - 1);
      frft_interp<<<dim3(64, 1), 256, 0, stream>>>(x, (__half*)d_ws, 255, 1, xi_cap, x_cap);
      frft_gemm<<<dim3(NN / TJ, 1), 256, 0, stream>>>(x, (__half*)d_ws, order, outf,
                                                      255, 1, xi_cap, x_cap, out_capf);
    } else {
      frft_gemm1<<<64, 256, 0, stream>>>(x, order, outf, x_cap, out_capf);
    }
  }
}

// Round 6
// 127.935 us; speedup vs baseline: 1.9016x; 1.2209x over previous
//
#include <hip/hip_runtime.h>
#include <hip/hip_fp16.h>
#include <math.h>

// FrFT (Ozaktas, 0.5<a<1.5): x[256,4096] f32, order f32 -> Re(complex64) f32
// out[b*4096+j]. R19: fix R5's measured diseases with the m214-proven LDS
// pattern + 4 waves/SIMD.
//   R5 bug: XOR-slot layout had slot stride 1024B == 0 mod 128 -> XOR never
//   changed the bank; staging writes were 8-way conflicted (14.7M conflicts).
//   Now: row-major U[2][64][256] halves (row 512B), in-row byte XOR
//   ((row&7)<<4) on BOTH write and read. Write = 2-way (free), read =
//   conflict-free across each contiguous-8-lane group.
//   Occupancy: 256 blocks x 1024 thr (16 waves = kq8 x fh2), CHW=256 ->
//   4 waves/SIMD (was 2). Per-wave math unchanged (2 cos/MFMA minimum).
//   Reduce: 8 kq-partials -> 2 LDS planes in 4 barrier rounds, no atomics.
// Weight math identical to proven R14-R18 (quadratic phase, __cosf,
// __fdividef); odd pad r=8191 weight-zeroed.

#define NN 4096
#define BB 256
#define KK (2*NN - 1)
#define CHW 256

typedef unsigned int uint;
typedef __attribute__((ext_vector_type(4))) float f32x4;
typedef __attribute__((ext_vector_type(4))) uint u32x4;
typedef __attribute__((ext_vector_type(8))) _Float16 half8;
typedef __attribute__((ext_vector_type(4))) _Float16 half4;

struct LitConsts { float c, q, scale, pe; };

__device__ __forceinline__ LitConsts get_lit(const float* order) {
  float a = order[0];
  float alpha = a * (float)M_PI * 0.5f;
  float sina = sinf(alpha);
  float tana2 = tanf(alpha * 0.5f);
  LitConsts L;
  L.c = (float)M_PI / (float)NN / sina / 4.0f;
  L.q = ((float)M_PI / (float)NN) * (tana2 * 0.25f);
  L.scale = sqrtf(L.c / (float)M_PI);
  L.pe = -(1.0f - a) * (float)M_PI * 0.25f;
  return L;
}

__device__ __forceinline__ float xload(const float* __restrict__ x, uint idx, uint cap) {
  return (idx < cap) ? x[idx] : 0.f;
}

// ---- stage 1: sinc interp GEMM; 256 blocks x 1024 thr; tile 64b x 64s ----
__global__ __launch_bounds__(1024, 4) void s1_v3(const float* __restrict__ x,
                                                 _Float16* __restrict__ xiT) {
  __shared__ __align__(16) _Float16 U[2][64][CHW];   // 64 KB (row = 512 B)
  __shared__ __align__(16) float red[2][64][68];     // 34.8 KB
  const int tid = threadIdx.x;
  const int w = tid >> 6, lane = tid & 63;
  const int l15 = lane & 15, lhi = lane >> 4;
  const int kq = w & 7, fh = w >> 3;
  const int id = blockIdx.x, xcd = id & 7;
  const int b0 = (xcd >> 1) * 64;                    // same-b blocks -> XCD
  const int s0 = ((xcd & 1) | ((id >> 3) << 1)) * 64;
  const int srow = tid >> 4;                         // 0..63 (16 thr/row)
  const int scb = (tid & 15) * 32;                   // in-row byte base (32 B/thr)
  const int swz = (srow & 7) << 4;                   // write-side XOR
  const int rdo = (kq * 64 + lhi * 16) ^ ((l15 & 7) << 4);  // read in-row byte
  const float C2PI = 0.63661977236758134f;

  f32x4 acc[4][2] = {};
  f32x4 pf[4];

  { // prologue: stage chunk 0
    const float* p = x + (size_t)(b0 + srow) * NN + (tid & 15) * 16;
#pragma unroll
    for (int q = 0; q < 4; ++q) pf[q] = ((const f32x4*)p)[q];
    half8 h0, h1;
#pragma unroll
    for (int e = 0; e < 4; ++e) {
      h0[e] = (_Float16)pf[0][e]; h0[e+4] = (_Float16)pf[1][e];
      h1[e] = (_Float16)pf[2][e]; h1[e+4] = (_Float16)pf[3][e];
    }
    char* base = (char*)&U[0][srow][0];
    *(half8*)(base + (scb ^ swz)) = h0;
    *(half8*)(base + ((scb + 16) ^ swz)) = h1;
  }

  for (int ch = 0; ch < 16; ++ch) {
    __syncthreads();
    const int cb = ch & 1;
    if (ch < 15) {
      const float* p = x + (size_t)(b0 + srow) * NN + (ch + 1) * CHW + (tid & 15) * 16;
#pragma unroll
      for (int q = 0; q < 4; ++q) pf[q] = ((const f32x4*)p)[q];
    }
    half8 af[4];
    const char* ub = (const char*)&U[cb][0][0];
#pragma unroll
    for (int fm = 0; fm < 4; ++fm)
      af[fm] = *(const half8*)(ub + (fm * 16 + l15) * (CHW * 2) + rdo);
    const int i0 = ch * CHW + kq * 32 + lhi * 8;
#pragma unroll
    for (int g = 0; g < 2; ++g) {
      const int t0 = (s0 + (fh * 2 + g) * 16 + l15) - i0;
      half8 bh;
#pragma unroll
      for (int e = 0; e < 8; ++e) {
        const int t = t0 - e;
        const float sgn = (t & 1) ? -C2PI : C2PI;
        bh[e] = (_Float16)__fdividef(sgn, (float)(2 * t + 1));
      }
#pragma unroll
      for (int fm = 0; fm < 4; ++fm)
        acc[fm][g] = __builtin_amdgcn_mfma_f32_16x16x32_f16(af[fm], bh, acc[fm][g], 0, 0, 0);
    }
    if (ch < 15) {
      half8 h0, h1;
#pragma unroll
      for (int e = 0; e < 4; ++e) {
        h0[e] = (_Float16)pf[0][e]; h0[e+4] = (_Float16)pf[1][e];
        h1[e] = (_Float16)pf[2][e]; h1[e+4] = (_Float16)pf[3][e];
      }
      char* base = (char*)&U[cb ^ 1][srow][0];
      *(half8*)(base + (scb ^ swz)) = h0;
      *(half8*)(base + ((scb + 16) ^ swz)) = h1;
    }
  }

  // 8 kq-partials -> red[2] planes in 4 barrier rounds
#pragma unroll
  for (int rnd = 0; rnd < 4; ++rnd) {
    __syncthreads();
    if ((kq >> 1) == rnd) {
      const int pl = kq & 1;
#pragma unroll
      for (int fm = 0; fm < 4; ++fm)
#pragma unroll
        for (int g = 0; g < 2; ++g)
#pragma unroll
          for (int rr = 0; rr < 4; ++rr) {
            float* p = &red[pl][fm * 16 + lhi * 4 + rr][(fh * 2 + g) * 16 + l15];
            if (rnd == 0) *p = acc[fm][g][rr];
            else          *p += acc[fm][g][rr];
          }
    }
  }
  __syncthreads();

  const int c0 = (tid & 15) * 4;
  half4 h;
#pragma unroll
  for (int e = 0; e < 4; ++e)
    h[e] = (_Float16)(red[0][srow][c0 + e] + red[1][srow][c0 + e]);
  *(half4*)(xiT + (size_t)(b0 + srow) * NN + s0 + c0) = h;
}

// ---- stage 2: fused even+odd chirp GEMM; 256 blocks x 1024 thr ----
__global__ __launch_bounds__(1024, 4) void s2_v3(const float* __restrict__ x,
                                                 const _Float16* __restrict__ xiT,
                                                 const float* __restrict__ order,
                                                 float* __restrict__ out) {
  __shared__ __align__(16) _Float16 U[2][64][CHW];
  __shared__ __align__(16) float red[2][64][68];
  const int tid = threadIdx.x;
  const int w = tid >> 6, lane = tid & 63;
  const int l15 = lane & 15, lhi = lane >> 4;
  const int kq = w & 7, fh = w >> 3;
  const int id = blockIdx.x, xcd = id & 7;
  const int b0 = (xcd >> 1) * 64;
  const int j0 = ((xcd & 1) | ((id >> 3) << 1)) * 64;
  const int srow = tid >> 4;
  const int scb = (tid & 15) * 32;
  const int swz = (srow & 7) << 4;
  const int rdo = (kq * 64 + lhi * 16) ^ ((l15 & 7) << 4);

  const LitConsts L = get_lit(order);
  const float P2 = 4.f * (L.c - L.q);
  int jl[2]; float jbase[2];
#pragma unroll
  for (int g = 0; g < 2; ++g) {
    jl[g] = j0 + (fh * 2 + g) * 16 + l15;
    const int n = 2 * jl[g] - (NN - 1);
    jbase[g] = fmaf(-L.q, (float)(n * n), L.pe);
  }

  f32x4 acc[4][2] = {};
  f32x4 pf[4];
  u32x4 ph2[2];

  { // prologue: stage even chunk 0
    const float* p = x + (size_t)(b0 + srow) * NN + (tid & 15) * 16;
#pragma unroll
    for (int q = 0; q < 4; ++q) pf[q] = ((const f32x4*)p)[q];
    half8 h0, h1;
#pragma unroll
    for (int e = 0; e < 4; ++e) {
      h0[e] = (_Float16)pf[0][e]; h0[e+4] = (_Float16)pf[1][e];
      h1[e] = (_Float16)pf[2][e]; h1[e+4] = (_Float16)pf[3][e];
    }
    char* base = (char*)&U[0][srow][0];
    *(half8*)(base + (scb ^ swz)) = h0;
    *(half8*)(base + ((scb + 16) ^ swz)) = h1;
  }

  // EVEN pass (r = 2i, A from x)
  for (int ch = 0; ch < 16; ++ch) {
    __syncthreads();
    const int cb = ch & 1;
    if (ch < 15) {
      const float* p = x + (size_t)(b0 + srow) * NN + (ch + 1) * CHW + (tid & 15) * 16;
#pragma unroll
      for (int q = 0; q < 4; ++q) pf[q] = ((const f32x4*)p)[q];
    } else {  // boundary: prefetch odd chunk 0 from xiT
      const _Float16* p = xiT + (size_t)(b0 + srow) * NN + (tid & 15) * 16;
      ph2[0] = ((const u32x4*)p)[0];
      ph2[1] = ((const u32x4*)p)[1];
    }
    half8 af[4];
    const char* ub = (const char*)&U[cb][0][0];
#pragma unroll
    for (int fm = 0; fm < 4; ++fm)
      af[fm] = *(const half8*)(ub + (fm * 16 + l15) * (CHW * 2) + rdo);
    const int i0 = ch * CHW + kq * 32 + lhi * 8;
    const int r0 = 2 * i0;
    const int k0 = r0 - (NN - 1);
    const float bk  = -L.q * (float)(k0 * k0);
    const float qk0 =  L.q * (float)k0;
#pragma unroll
    for (int g = 0; g < 2; ++g) {
      const int d0 = 2 * jl[g] - r0;
      const float P0 = fmaf(L.c, (float)(d0 * d0), jbase[g] + bk);
      const float P1 = -4.f * fmaf(L.c, (float)d0, qk0);
      half8 bh;
#pragma unroll
      for (int e = 0; e < 8; ++e) {
        const float ef = (float)e;
        bh[e] = (_Float16)__cosf(fmaf(ef, fmaf(ef, P2, P1), P0));
      }
#pragma unroll
      for (int fm = 0; fm < 4; ++fm)
        acc[fm][g] = __builtin_amdgcn_mfma_f32_16x16x32_f16(af[fm], bh, acc[fm][g], 0, 0, 0);
    }
    char* base = (char*)&U[cb ^ 1][srow][0];
    if (ch < 15) {
      half8 h0, h1;
#pragma unroll
      for (int e = 0; e < 4; ++e) {
        h0[e] = (_Float16)pf[0][e]; h0[e+4] = (_Float16)pf[1][e];
        h1[e] = (_Float16)pf[2][e]; h1[e+4] = (_Float16)pf[3][e];
      }
      *(half8*)(base + (scb ^ swz)) = h0;
      *(half8*)(base + ((scb + 16) ^ swz)) = h1;
    } else {
      *(u32x4*)(base + (scb ^ swz)) = ph2[0];
      *(u32x4*)(base + ((scb + 16) ^ swz)) = ph2[1];
    }
  }

  // ODD pass (r = 2i+1, A from xiT)
  for (int ch = 0; ch < 16; ++ch) {
    __syncthreads();
    const int cb = ch & 1;
    if (ch < 15) {
      const _Float16* p = xiT + (size_t)(b0 + srow) * NN + (ch + 1) * CHW + (tid & 15) * 16;
      ph2[0] = ((const u32x4*)p)[0];
      ph2[1] = ((const u32x4*)p)[1];
    }
    half8 af[4];
    const char* ub = (const char*)&U[cb][0][0];
#pragma unroll
    for (int fm = 0; fm < 4; ++fm)
      af[fm] = *(const half8*)(ub + (fm * 16 + l15) * (CHW * 2) + rdo);
    const int i0 = ch * CHW + kq * 32 + lhi * 8;
    const int r0 = 2 * i0 + 1;
    const int k0 = r0 - (NN - 1);
    const float bk  = -L.q * (float)(k0 * k0);
    const float qk0 =  L.q * (float)k0;
#pragma unroll
    for (int g = 0; g < 2; ++g) {
      const int d0 = 2 * jl[g] - r0;
      const float P0 = fmaf(L.c, (float)(d0 * d0), jbase[g] + bk);
      const float P1 = -4.f * fmaf(L.c, (float)d0, qk0);
      half8 bh;
#pragma unroll
      for (int e = 0; e < 8; ++e) {
        const float ef = (float)e;
        float wv = __cosf(fmaf(ef, fmaf(ef, P2, P1), P0));
        if (i0 + e > NN - 2) wv = 0.f;   // r=8191 pad does not exist
        bh[e] = (_Float16)wv;
      }
#pragma unroll
      for (int fm = 0; fm < 4; ++fm)
        acc[fm][g] = __builtin_amdgcn_mfma_f32_16x16x32_f16(af[fm], bh, acc[fm][g], 0, 0, 0);
    }
    if (ch < 15) {
      char* base = (char*)&U[cb ^ 1][srow][0];
      *(u32x4*)(base + (scb ^ swz)) = ph2[0];
      *(u32x4*)(base + ((scb + 16) ^ swz)) = ph2[1];
    }
  }

  // reduce + scaled store
#pragma unroll
  for (int rnd = 0; rnd < 4; ++rnd) {
    __syncthreads();
    if ((kq >> 1) == rnd) {
      const int pl = kq & 1;
#pragma unroll
      for (int fm = 0; fm < 4; ++fm)
#pragma unroll
        for (int g = 0; g < 2; ++g)
#pragma unroll
          for (int rr = 0; rr < 4; ++rr) {
            float* p = &red[pl][fm * 16 + lhi * 4 + rr][(fh * 2 + g) * 16 + l15];
            if (rnd == 0) *p = acc[fm][g][rr];
            else          *p += acc[fm][g][rr];
          }
    }
  }
  __syncthreads();

  const int c0 = (tid & 15) * 4;
  f32x4 v;
#pragma unroll
  for (int e = 0; e < 4; ++e)
    v[e] = L.scale * (red[0][srow][c0 + e] + red[1][srow][c0 + e]);
  *(f32x4*)(out + (size_t)(b0 + srow) * NN + j0 + c0) = v;
}

// ======================= R13 proven fallback (small ws) =======================

__global__ __launch_bounds__(256) void frft_interp(const float* __restrict__ x,
                                                   __half* __restrict__ xi,
                                                   int b_lo, int cnt,
                                                   uint xi_cap, uint x_cap) {
  __shared__ __align__(16) float wt1[32][64];
  __shared__ __align__(16) float xt[32][64];
  const int tid = threadIdx.x;
  const int s0 = blockIdx.x * 64, cb0 = blockIdx.y * 64;
  const int tx = tid & 15, ty = tid >> 4;
  const int ss0 = ty * 4, bb0 = tx * 4;

  float acc[4][4] = {};
  for (int i0 = 0; i0 < NN; i0 += 32) {
#pragma unroll
    for (int e = 0; e < 8; ++e) {
      int idx = tid + e * 256, qq = idx >> 6, ss = idx & 63;
      int t = s0 + ss - (i0 + qq);
      float sgn = (t & 1) ? -0.63661977236758134f : 0.63661977236758134f;
      wt1[qq][ss] = __fdividef(sgn, (float)(2 * t + 1));
    }
#pragma unroll
    for (int e = 0; e < 8; ++e) {
      int idx = tid + e * 256, qq = idx >> 6, bb = idx & 63;
      xt[qq][bb] = xload(x, (uint)(b_lo + cb0 + bb) * NN + (i0 + qq), x_cap);
    }
    __syncthreads();
#pragma unroll
    for (int qq = 0; qq < 32; ++qq) {
      float4 wv = *(const float4*)&wt1[qq][ss0];
      float4 uv = *(const float4*)&xt[qq][bb0];
      float w[4] = {wv.x, wv.y, wv.z, wv.w};
      float u[4] = {uv.x, uv.y, uv.z, uv.w};
#pragma unroll
      for (int aa = 0; aa < 4; ++aa)
#pragma unroll
        for (int cc = 0; cc < 4; ++cc) acc[aa][cc] = fmaf(w[aa], u[cc], acc[aa][cc]);
    }
    __syncthreads();
  }
#pragma unroll
  for (int aa = 0; aa < 4; ++aa) {
    int s = s0 + ss0 + aa;
    if (s < NN - 1) {
#pragma unroll
      for (int cc = 0; cc < 4; ++cc) {
        int cb = cb0 + bb0 + cc;
        if (cb < cnt) {
          uint o = (uint)s * (uint)cnt + (uint)cb;
          if (o < xi_cap) xi[o] = __float2half(acc[aa][cc]);
        }
      }
    }
  }
}

#define TJ 32
#define TB 64
#define TK 32
__global__ __launch_bounds__(256) void frft_gemm(const float* __restrict__ x,
                                                 const __half* __restrict__ xi,
                                                 const float* __restrict__ order,
                                                 float* __restrict__ out,
                                                 int b_lo, int cnt,
                                                 uint xi_cap, uint x_cap,
                                                 uint out_capf) {
  __shared__ __align__(16) float wt[TK][TJ];
  __shared__ __align__(16) float ut[TK][TB];
  const int tid = threadIdx.x;
  const int j0 = blockIdx.x * TJ, cb0 = blockIdx.y * TB;
  const int tx = tid & 15, ty = tid >> 4;
  const int jj0 = ty * 2, bb0 = tx * 4;

  LitConsts L = get_lit(order);
  float acc[2][4] = {};

  for (int r0 = 0; r0 < KK; r0 += TK) {
#pragma unroll
    for (int e = 0; e < 4; ++e) {
      int idx = tid + e * 256, qq = idx >> 5, jj = idx & 31;
      int r = r0 + qq;
      float wv = 0.f;
      if (r < KK) {
        int j = j0 + jj;
        int n = 2 * j - (NN - 1);
        int d = 2 * j - r;
        int k = r - (NN - 1);
        float base = fmaf(-L.q, (float)(n * n), L.pe);
        float ph = fmaf(L.c, (float)(d * d), fmaf(-L.q, (float)(k * k), base));
        wv = __cosf(ph);
      }
      wt[qq][jj] = wv;
    }
#pragma unroll
    for (int e = 0; e < 8; ++e) {
      int idx = tid + e * 256, qq = idx >> 6, bb = idx & 63;
      int r = r0 + qq, cb = cb0 + bb;
      float v = 0.f;
      if (r < KK && cb < cnt) {
        if (r & 1) {
          uint o = (uint)(r >> 1) * (uint)cnt + (uint)cb;
          v = (o < xi_cap) ? __half2float(xi[o]) : 0.f;
        } else {
          v = xload(x, (uint)(b_lo + cb) * NN + (uint)(r >> 1), x_cap);
        }
      }
      ut[qq][bb] = v;
    }
    __syncthreads();
#pragma unroll
    for (int qq = 0; qq < TK; ++qq) {
      float2 wv = *(const float2*)&wt[qq][jj0];
      float4 uv = *(const float4*)&ut[qq][bb0];
      float w[2] = {wv.x, wv.y};
      float u[4] = {uv.x, uv.y, uv.z, uv.w};
#pragma unroll
      for (int aa = 0; aa < 2; ++aa)
#pragma unroll
        for (int cc = 0; cc < 4; ++cc)
          acc[aa][cc] = fmaf(w[aa], u[cc], acc[aa][cc]);
    }
    __syncthreads();
  }

#pragma unroll
  for (int aa = 0; aa < 2; ++aa) {
    int j = j0 + jj0 + aa;
#pragma unroll
    for (int cc = 0; cc < 4; ++cc) {
      int cb = cb0 + bb0 + cc;
      if (cb < cnt) {
        uint idx = (uint)(b_lo + cb) * NN + (uint)j;
        if (idx < out_capf) out[idx] = L.scale * acc[aa][cc];
      }
    }
  }
}

__global__ __launch_bounds__(256) void frft_gemm1(const float* __restrict__ x,
                                                  const float* __restrict__ order,
                                                  float* __restrict__ out,
                                                  uint x_cap, uint out_capf) {
  __shared__ float xrow[NN];
  __shared__ float xio[NN - 1];
  __shared__ float red[4][64];
  const int tid = threadIdx.x;
  const int j0 = blockIdx.x * 64;
  LitConsts L = get_lit(order);

#pragma unroll
  for (int e = 0; e < 16; ++e) {
    int i = tid + e * 256;
    xrow[i] = xload(x, (uint)255 * NN + (uint)i, x_cap);
  }
  __syncthreads();
#pragma unroll
  for (int m = 0; m < 16; ++m) {
    int s = tid + m * 256;
    if (s < NN - 1) {
      float a0 = 0.f;
      for (int i = 0; i < NN; ++i) {
        int t = s - i;
        float sgn = (t & 1) ? -0.63661977236758134f : 0.63661977236758134f;
        a0 = fmaf(xrow[i], __fdividef(sgn, (float)(2 * t + 1)), a0);
      }
      xio[s] = a0;
    }
  }
  __syncthreads();

  const int ty = tid >> 6, jj = tid & 63;
  const int j = j0 + jj;
  const int n = 2 * j - (NN - 1);
  const float base = fmaf(-L.q, (float)(n * n), L.pe);
  float acc = 0.f;
  int rend = (ty + 1) * 2048; if (rend > KK) rend = KK;
  for (int r = ty * 2048; r < rend; ++r) {
    int d = 2 * j - r;
    int k = r - (NN - 1);
    float ph = fmaf(L.c, (float)(d * d), fmaf(-L.q, (float)(k * k), base));
    float u = (r & 1) ? xio[r >> 1] : xrow[r >> 1];
    acc = fmaf(__cosf(ph), u, acc);
  }
  red[ty][jj] = acc;
  __syncthreads();
  if (ty == 0) {
    float t = red[0][jj] + red[1][jj] + red[2][jj] + red[3][jj];
    uint idx = (uint)255 * NN + (uint)j;
    if (idx < out_capf) out[idx] = L.scale * t;
  }
}

extern "C" void kernel_launch(void* const* d_in, const int* in_sizes, int n_in,
                              void* d_out, int out_size, void* d_ws, size_t ws_size,
                              hipStream_t stream) {
  const float* x     = (const float*)d_in[0];
  const float* order = (const float*)d_in[1];
  float* outf = (float*)d_out;
  const uint x_cap    = (uint)in_sizes[0];
  const uint out_capf = (uint)out_size;
  const size_t ws_halves = ws_size / 2;

  // ---- R19 conflict-free LDS-staged MFMA path, 4 waves/SIMD ----
  if (ws_size >= (size_t)NN * BB * 2 &&
      out_capf >= (uint)NN * BB && x_cap >= (uint)NN * BB) {
    _Float16* xiT = (_Float16*)d_ws;
    s1_v3<<<dim3(256), 1024, 0, stream>>>(x, xiT);
    s2_v3<<<dim3(256), 1024, 0, stream>>>(x, xiT, order, outf);
    return;
  }

  // ---- R13 proven fallback paths ----
  if (ws_halves >= (size_t)(NN - 1) * BB) {
    uint xi_cap = (uint)((size_t)(NN - 1) * BB);
    frft_interp<<<dim3(64, 4), 256, 0, stream>>>(x, (__half*)d_ws, 0, BB, xi_cap, x_cap);
    frft_gemm<<<dim3(NN / TJ, BB / TB), 256, 0, stream>>>(x, (__half*)d_ws, order, outf,
                                                          0, BB, xi_cap, x_cap, out_capf);
  } else {
    struct Chunk { int lo, cnt; };
    const Chunk ch[6] = { {0,170}, {170,57}, {227,19}, {246,6}, {252,2}, {254,1} };
    for (int i = 0; i < 6; ++i) {
      const Chunk& c = ch[i];
      uint off = (uint)(c.lo + c.cnt) * (uint)NN;
      __half* xp = (__half*)(outf + off);
      size_t need = (size_t)(NN - 1) * (size_t)c.cnt;
      size_t avail = (out_capf > off) ? (size_t)(out_capf - off) * 2 : 0;
      uint xi_cap = (uint)(need < avail ? need : avail);
      frft_interp<<<dim3(64, (unsigned)((c.cnt + 63) / 64)), 256, 0, stream>>>(
          x, xp, c.lo, c.cnt, xi_cap, x_cap);
      frft_gemm<<<dim3(NN / TJ, (unsigned)((c.cnt + TB - 1) / TB)), 256, 0, stream>>>(
          x, xp, order, outf, c.lo, c.cnt, xi_cap, x_cap, out_capf);
    }
    if (ws_halves >= (size_t)(NN - 1)) {
      uint xi_cap = (uint)(NN - 1);
      frft_interp<<<dim3(64, 1), 256, 0, stream>>>(x, (__half*)d_ws, 255, 1, xi_cap, x_cap);
      frft_gemm<<<dim3(NN / TJ, 1), 256, 0, stream>>>(x, (__half*)d_ws, order, outf,
                                                      255, 1, xi_cap, x_cap, out_capf);
    } else {
      frft_gemm1<<<64, 256, 0, stream>>>(x, order, outf, x_cap, out_capf);
    }
  }
}

// Round 8
// 124.354 us; speedup vs baseline: 1.9564x; 1.0288x over previous
//
#include <hip/hip_runtime.h>
#include <hip/hip_fp16.h>
#include <math.h>

// FrFT (Ozaktas, 0.5<a<1.5): x[256,4096] f32, order f32 -> Re(complex64) f32
// out[b*4096+j]. R21 = R20 with the cvt_pkrtz type fix (builtin returns
// __fp16x2, not _Float16x2 -> bit_cast).
//   R6 lesson: any within-row permutation of a contiguous 512B row write by
//   16 lanes covers only 4 bank positions -> the fix must change WHICH
//   granules a thread writes. Thread t15 stages strided granules
//   {t15,t15+16,t15+32,t15+48}; LDS position = (s ^ (s>>3))*16B, XOR'd with
//   ((row&7)<<4); enumerated: every 16-lane write AND read instruction hits
//   all 8 bank positions x2 (free).
//   CHW=512 (whole row per chunk): barriers 32->16 (s2), 16->8 (s1).
//   red aliased into U (dead after k-loop); v_cvt_pkrtz for staging+weights.
// Weight math identical to proven R14-R19 (quadratic phase, __cosf,
// __fdividef); odd pad r=8191 weight-zeroed. f16 pack now RTZ (<=1ulp).

#define NN 4096
#define BB 256
#define KK (2*NN - 1)
#define CHW 512

typedef unsigned int uint;
typedef __attribute__((ext_vector_type(4))) float f32x4;
typedef __attribute__((ext_vector_type(4))) uint u32x4;
typedef __attribute__((ext_vector_type(8))) _Float16 half8;
typedef __attribute__((ext_vector_type(4))) _Float16 half4;
typedef __attribute__((ext_vector_type(2))) __fp16 fp16x2;

struct LitConsts { float c, q, scale, pe; };

__device__ __forceinline__ LitConsts get_lit(const float* order) {
  float a = order[0];
  float alpha = a * (float)M_PI * 0.5f;
  float sina = sinf(alpha);
  float tana2 = tanf(alpha * 0.5f);
  LitConsts L;
  L.c = (float)M_PI / (float)NN / sina / 4.0f;
  L.q = ((float)M_PI / (float)NN) * (tana2 * 0.25f);
  L.scale = sqrtf(L.c / (float)M_PI);
  L.pe = -(1.0f - a) * (float)M_PI * 0.25f;
  return L;
}

__device__ __forceinline__ float xload(const float* __restrict__ x, uint idx, uint cap) {
  return (idx < cap) ? x[idx] : 0.f;
}

__device__ __forceinline__ uint pk2(float a, float b) {
  fp16x2 h = __builtin_amdgcn_cvt_pkrtz(a, b);
  return __builtin_bit_cast(uint, h);
}

__device__ __forceinline__ half8 pack8(const float* wv) {
  u32x4 u = { pk2(wv[0], wv[1]), pk2(wv[2], wv[3]),
              pk2(wv[4], wv[5]), pk2(wv[6], wv[7]) };
  return __builtin_bit_cast(half8, u);
}

// granule position permutation (16B granules within a 64-granule row)
__device__ __forceinline__ int gpos(int s) { return s ^ (s >> 3); }

// ---- stage 1: sinc interp GEMM; 256 blocks x 1024 thr; tile 64b x 64s ----
__global__ __launch_bounds__(1024, 4) void s1_v4(const float* __restrict__ x,
                                                 _Float16* __restrict__ xiT) {
  __shared__ __align__(16) _Float16 U[2][64][CHW];   // 128 KB
  float* redf = (float*)&U[0][0][0];                 // aliased after k-loop
  const int tid = threadIdx.x;
  const int w = tid >> 6, lane = tid & 63;
  const int l15 = lane & 15, lhi = lane >> 4;
  const int kq = w & 7, fh = w >> 3;
  const int id = blockIdx.x, xcd = id & 7;
  const int b0 = (xcd >> 1) * 64;                    // same-b blocks -> XCD
  const int s0 = ((xcd & 1) | ((id >> 3) << 1)) * 64;
  const int srow = tid >> 4, t15 = tid & 15;
  const int swz = (srow & 7) << 4;
  const float C2PI = 0.63661977236758134f;

  const float* xrow = x + (size_t)(b0 + srow) * NN;

  f32x4 acc[4][2] = {};
  f32x4 pf[4][2];

  { // prologue: stage chunk 0
#pragma unroll
    for (int k = 0; k < 4; ++k) {
      const f32x4* p = (const f32x4*)(xrow + (t15 + 16 * k) * 8);
      f32x4 a = p[0], b = p[1];
      u32x4 d = { pk2(a[0], a[1]), pk2(a[2], a[3]), pk2(b[0], b[1]), pk2(b[2], b[3]) };
      const int s = t15 + 16 * k;
      *(u32x4*)((char*)&U[0][srow][0] + ((gpos(s) << 4) ^ swz)) = d;
    }
  }

  for (int ch = 0; ch < 8; ++ch) {
    __syncthreads();
    const int cb = ch & 1;
    if (ch < 7) {
#pragma unroll
      for (int k = 0; k < 4; ++k) {
        const f32x4* p = (const f32x4*)(xrow + (ch + 1) * CHW + (t15 + 16 * k) * 8);
        pf[k][0] = p[0]; pf[k][1] = p[1];
      }
    }
#pragma unroll
    for (int st = 0; st < 2; ++st) {
      const int sg = kq * 8 + st * 4 + lhi;
      const int go = gpos(sg) << 4;
      half8 af[4];
#pragma unroll
      for (int fm = 0; fm < 4; ++fm) {
        const int row = fm * 16 + l15;
        af[fm] = *(const half8*)((const char*)&U[cb][row][0] + (go ^ ((row & 7) << 4)));
      }
      const int i0 = ch * CHW + kq * 64 + st * 32 + lhi * 8;
#pragma unroll
      for (int g = 0; g < 2; ++g) {
        const int t0 = (s0 + (fh * 2 + g) * 16 + l15) - i0;
        float wv[8];
#pragma unroll
        for (int e = 0; e < 8; ++e) {
          const int t = t0 - e;
          const float sgn = (t & 1) ? -C2PI : C2PI;
          wv[e] = __fdividef(sgn, (float)(2 * t + 1));
        }
        const half8 bh = pack8(wv);
#pragma unroll
        for (int fm = 0; fm < 4; ++fm)
          acc[fm][g] = __builtin_amdgcn_mfma_f32_16x16x32_f16(af[fm], bh, acc[fm][g], 0, 0, 0);
      }
    }
    if (ch < 7) {
      char* base = (char*)&U[cb ^ 1][srow][0];
#pragma unroll
      for (int k = 0; k < 4; ++k) {
        u32x4 d = { pk2(pf[k][0][0], pf[k][0][1]), pk2(pf[k][0][2], pf[k][0][3]),
                    pk2(pf[k][1][0], pf[k][1][1]), pk2(pf[k][1][2], pf[k][1][3]) };
        const int s = t15 + 16 * k;
        *(u32x4*)(base + ((gpos(s) << 4) ^ swz)) = d;
      }
    }
  }

  // 8 kq-partials -> 2 red planes (aliased over U) in 4 barrier rounds
#pragma unroll
  for (int rnd = 0; rnd < 4; ++rnd) {
    __syncthreads();
    if ((kq >> 1) == rnd) {
      const int pl = kq & 1;
#pragma unroll
      for (int fm = 0; fm < 4; ++fm)
#pragma unroll
        for (int g = 0; g < 2; ++g)
#pragma unroll
          for (int rr = 0; rr < 4; ++rr) {
            float* p = &redf[((pl * 64) + fm * 16 + lhi * 4 + rr) * 68 + (fh * 2 + g) * 16 + l15];
            if (rnd == 0) *p = acc[fm][g][rr];
            else          *p += acc[fm][g][rr];
          }
    }
  }
  __syncthreads();

  const int c0 = t15 * 4;
  half4 h;
#pragma unroll
  for (int e = 0; e < 4; ++e)
    h[e] = (_Float16)(redf[(srow) * 68 + c0 + e] + redf[(64 + srow) * 68 + c0 + e]);
  *(half4*)(xiT + (size_t)(b0 + srow) * NN + s0 + c0) = h;
}

// ---- stage 2: fused even+odd chirp GEMM; 256 blocks x 1024 thr ----
__global__ __launch_bounds__(1024, 4) void s2_v4(const float* __restrict__ x,
                                                 const _Float16* __restrict__ xiT,
                                                 const float* __restrict__ order,
                                                 float* __restrict__ out) {
  __shared__ __align__(16) _Float16 U[2][64][CHW];
  float* redf = (float*)&U[0][0][0];
  const int tid = threadIdx.x;
  const int w = tid >> 6, lane = tid & 63;
  const int l15 = lane & 15, lhi = lane >> 4;
  const int kq = w & 7, fh = w >> 3;
  const int id = blockIdx.x, xcd = id & 7;
  const int b0 = (xcd >> 1) * 64;
  const int j0 = ((xcd & 1) | ((id >> 3) << 1)) * 64;
  const int srow = tid >> 4, t15 = tid & 15;
  const int swz = (srow & 7) << 4;

  const LitConsts L = get_lit(order);
  const float P2 = 4.f * (L.c - L.q);
  int jl[2]; float jbase[2];
#pragma unroll
  for (int g = 0; g < 2; ++g) {
    jl[g] = j0 + (fh * 2 + g) * 16 + l15;
    const int n = 2 * jl[g] - (NN - 1);
    jbase[g] = fmaf(-L.q, (float)(n * n), L.pe);
  }

  const float* xrow = x + (size_t)(b0 + srow) * NN;
  const _Float16* orow = xiT + (size_t)(b0 + srow) * NN;

  f32x4 acc[4][2] = {};
  f32x4 pf[4][2];
  u32x4 po[4];

  { // prologue: stage even chunk 0
#pragma unroll
    for (int k = 0; k < 4; ++k) {
      const f32x4* p = (const f32x4*)(xrow + (t15 + 16 * k) * 8);
      f32x4 a = p[0], b = p[1];
      u32x4 d = { pk2(a[0], a[1]), pk2(a[2], a[3]), pk2(b[0], b[1]), pk2(b[2], b[3]) };
      const int s = t15 + 16 * k;
      *(u32x4*)((char*)&U[0][srow][0] + ((gpos(s) << 4) ^ swz)) = d;
    }
  }

  // EVEN pass (r = 2i, A from x); ch=7 prefetches odd chunk 0 from xiT
  for (int ch = 0; ch < 8; ++ch) {
    __syncthreads();
    const int cb = ch & 1;
    if (ch < 7) {
#pragma unroll
      for (int k = 0; k < 4; ++k) {
        const f32x4* p = (const f32x4*)(xrow + (ch + 1) * CHW + (t15 + 16 * k) * 8);
        pf[k][0] = p[0]; pf[k][1] = p[1];
      }
    } else {
#pragma unroll
      for (int k = 0; k < 4; ++k)
        po[k] = *(const u32x4*)(orow + (t15 + 16 * k) * 8);
    }
#pragma unroll
    for (int st = 0; st < 2; ++st) {
      const int sg = kq * 8 + st * 4 + lhi;
      const int go = gpos(sg) << 4;
      half8 af[4];
#pragma unroll
      for (int fm = 0; fm < 4; ++fm) {
        const int row = fm * 16 + l15;
        af[fm] = *(const half8*)((const char*)&U[cb][row][0] + (go ^ ((row & 7) << 4)));
      }
      const int i0 = ch * CHW + kq * 64 + st * 32 + lhi * 8;
      const int r0 = 2 * i0;
      const int k0 = r0 - (NN - 1);
      const float bk  = -L.q * (float)(k0 * k0);
      const float qk0 =  L.q * (float)k0;
#pragma unroll
      for (int g = 0; g < 2; ++g) {
        const int d0 = 2 * jl[g] - r0;
        const float P0 = fmaf(L.c, (float)(d0 * d0), jbase[g] + bk);
        const float P1 = -4.f * fmaf(L.c, (float)d0, qk0);
        float wv[8];
#pragma unroll
        for (int e = 0; e < 8; ++e) {
          const float ef = (float)e;
          wv[e] = __cosf(fmaf(ef, fmaf(ef, P2, P1), P0));
        }
        const half8 bh = pack8(wv);
#pragma unroll
        for (int fm = 0; fm < 4; ++fm)
          acc[fm][g] = __builtin_amdgcn_mfma_f32_16x16x32_f16(af[fm], bh, acc[fm][g], 0, 0, 0);
      }
    }
    char* base = (char*)&U[cb ^ 1][srow][0];
    if (ch < 7) {
#pragma unroll
      for (int k = 0; k < 4; ++k) {
        u32x4 d = { pk2(pf[k][0][0], pf[k][0][1]), pk2(pf[k][0][2], pf[k][0][3]),
                    pk2(pf[k][1][0], pf[k][1][1]), pk2(pf[k][1][2], pf[k][1][3]) };
        const int s = t15 + 16 * k;
        *(u32x4*)(base + ((gpos(s) << 4) ^ swz)) = d;
      }
    } else {
#pragma unroll
      for (int k = 0; k < 4; ++k) {
        const int s = t15 + 16 * k;
        *(u32x4*)(base + ((gpos(s) << 4) ^ swz)) = po[k];
      }
    }
  }

  // ODD pass (r = 2i+1, A from xiT); odd chunk 0 already in U[0]
  for (int ch = 0; ch < 8; ++ch) {
    __syncthreads();
    const int cb = ch & 1;
    if (ch < 7) {
#pragma unroll
      for (int k = 0; k < 4; ++k)
        po[k] = *(const u32x4*)(orow + (ch + 1) * CHW + (t15 + 16 * k) * 8);
    }
#pragma unroll
    for (int st = 0; st < 2; ++st) {
      const int sg = kq * 8 + st * 4 + lhi;
      const int go = gpos(sg) << 4;
      half8 af[4];
#pragma unroll
      for (int fm = 0; fm < 4; ++fm) {
        const int row = fm * 16 + l15;
        af[fm] = *(const half8*)((const char*)&U[cb][row][0] + (go ^ ((row & 7) << 4)));
      }
      const int i0 = ch * CHW + kq * 64 + st * 32 + lhi * 8;
      const int r0 = 2 * i0 + 1;
      const int k0 = r0 - (NN - 1);
      const float bk  = -L.q * (float)(k0 * k0);
      const float qk0 =  L.q * (float)k0;
#pragma unroll
      for (int g = 0; g < 2; ++g) {
        const int d0 = 2 * jl[g] - r0;
        const float P0 = fmaf(L.c, (float)(d0 * d0), jbase[g] + bk);
        const float P1 = -4.f * fmaf(L.c, (float)d0, qk0);
        float wv[8];
#pragma unroll
        for (int e = 0; e < 8; ++e) {
          const float ef = (float)e;
          float t = __cosf(fmaf(ef, fmaf(ef, P2, P1), P0));
          if (i0 + e > NN - 2) t = 0.f;   // r=8191 pad does not exist
          wv[e] = t;
        }
        const half8 bh = pack8(wv);
#pragma unroll
        for (int fm = 0; fm < 4; ++fm)
          acc[fm][g] = __builtin_amdgcn_mfma_f32_16x16x32_f16(af[fm], bh, acc[fm][g], 0, 0, 0);
      }
    }
    if (ch < 7) {
      char* base = (char*)&U[cb ^ 1][srow][0];
#pragma unroll
      for (int k = 0; k < 4; ++k) {
        const int s = t15 + 16 * k;
        *(u32x4*)(base + ((gpos(s) << 4) ^ swz)) = po[k];
      }
    }
  }

  // reduce (red aliased over U[0]) + scaled store
#pragma unroll
  for (int rnd = 0; rnd < 4; ++rnd) {
    __syncthreads();
    if ((kq >> 1) == rnd) {
      const int pl = kq & 1;
#pragma unroll
      for (int fm = 0; fm < 4; ++fm)
#pragma unroll
        for (int g = 0; g < 2; ++g)
#pragma unroll
          for (int rr = 0; rr < 4; ++rr) {
            float* p = &redf[((pl * 64) + fm * 16 + lhi * 4 + rr) * 68 + (fh * 2 + g) * 16 + l15];
            if (rnd == 0) *p = acc[fm][g][rr];
            else          *p += acc[fm][g][rr];
          }
    }
  }
  __syncthreads();

  const int c0 = t15 * 4;
  f32x4 v;
#pragma unroll
  for (int e = 0; e < 4; ++e)
    v[e] = L.scale * (redf[(srow) * 68 + c0 + e] + redf[(64 + srow) * 68 + c0 + e]);
  *(f32x4*)(out + (size_t)(b0 + srow) * NN + j0 + c0) = v;
}

// ======================= R13 proven fallback (small ws) =======================

__global__ __launch_bounds__(256) void frft_interp(const float* __restrict__ x,
                                                   __half* __restrict__ xi,
                                                   int b_lo, int cnt,
                                                   uint xi_cap, uint x_cap) {
  __shared__ __align__(16) float wt1[32][64];
  __shared__ __align__(16) float xt[32][64];
  const int tid = threadIdx.x;
  const int s0 = blockIdx.x * 64, cb0 = blockIdx.y * 64;
  const int tx = tid & 15, ty = tid >> 4;
  const int ss0 = ty * 4, bb0 = tx * 4;

  float acc[4][4] = {};
  for (int i0 = 0; i0 < NN; i0 += 32) {
#pragma unroll
    for (int e = 0; e < 8; ++e) {
      int idx = tid + e * 256, qq = idx >> 6, ss = idx & 63;
      int t = s0 + ss - (i0 + qq);
      float sgn = (t & 1) ? -0.63661977236758134f : 0.63661977236758134f;
      wt1[qq][ss] = __fdividef(sgn, (float)(2 * t + 1));
    }
#pragma unroll
    for (int e = 0; e < 8; ++e) {
      int idx = tid + e * 256, qq = idx >> 6, bb = idx & 63;
      xt[qq][bb] = xload(x, (uint)(b_lo + cb0 + bb) * NN + (i0 + qq), x_cap);
    }
    __syncthreads();
#pragma unroll
    for (int qq = 0; qq < 32; ++qq) {
      float4 wv = *(const float4*)&wt1[qq][ss0];
      float4 uv = *(const float4*)&xt[qq][bb0];
      float w[4] = {wv.x, wv.y, wv.z, wv.w};
      float u[4] = {uv.x, uv.y, uv.z, uv.w};
#pragma unroll
      for (int aa = 0; aa < 4; ++aa)
#pragma unroll
        for (int cc = 0; cc < 4; ++cc) acc[aa][cc] = fmaf(w[aa], u[cc], acc[aa][cc]);
    }
    __syncthreads();
  }
#pragma unroll
  for (int aa = 0; aa < 4; ++aa) {
    int s = s0 + ss0 + aa;
    if (s < NN - 1) {
#pragma unroll
      for (int cc = 0; cc < 4; ++cc) {
        int cb = cb0 + bb0 + cc;
        if (cb < cnt) {
          uint o = (uint)s * (uint)cnt + (uint)cb;
          if (o < xi_cap) xi[o] = __float2half(acc[aa][cc]);
        }
      }
    }
  }
}

#define TJ 32
#define TB 64
#define TK 32
__global__ __launch_bounds__(256) void frft_gemm(const float* __restrict__ x,
                                                 const __half* __restrict__ xi,
                                                 const float* __restrict__ order,
                                                 float* __restrict__ out,
                                                 int b_lo, int cnt,
                                                 uint xi_cap, uint x_cap,
                                                 uint out_capf) {
  __shared__ __align__(16) float wt[TK][TJ];
  __shared__ __align__(16) float ut[TK][TB];
  const int tid = threadIdx.x;
  const int j0 = blockIdx.x * TJ, cb0 = blockIdx.y * TB;
  const int tx = tid & 15, ty = tid >> 4;
  const int jj0 = ty * 2, bb0 = tx * 4;

  LitConsts L = get_lit(order);
  float acc[2][4] = {};

  for (int r0 = 0; r0 < KK; r0 += TK) {
#pragma unroll
    for (int e = 0; e < 4; ++e) {
      int idx = tid + e * 256, qq = idx >> 5, jj = idx & 31;
      int r = r0 + qq;
      float wv = 0.f;
      if (r < KK) {
        int j = j0 + jj;
        int n = 2 * j - (NN - 1);
        int d = 2 * j - r;
        int k = r - (NN - 1);
        float base = fmaf(-L.q, (float)(n * n), L.pe);
        float ph = fmaf(L.c, (float)(d * d), fmaf(-L.q, (float)(k * k), base));
        wv = __cosf(ph);
      }
      wt[qq][jj] = wv;
    }
#pragma unroll
    for (int e = 0; e < 8; ++e) {
      int idx = tid + e * 256, qq = idx >> 6, bb = idx & 63;
      int r = r0 + qq, cb = cb0 + bb;
      float v = 0.f;
      if (r < KK && cb < cnt) {
        if (r & 1) {
          uint o = (uint)(r >> 1) * (uint)cnt + (uint)cb;
          v = (o < xi_cap) ? __half2float(xi[o]) : 0.f;
        } else {
          v = xload(x, (uint)(b_lo + cb) * NN + (uint)(r >> 1), x_cap);
        }
      }
      ut[qq][bb] = v;
    }
    __syncthreads();
#pragma unroll
    for (int qq = 0; qq < TK; ++qq) {
      float2 wv = *(const float2*)&wt[qq][jj0];
      float4 uv = *(const float4*)&ut[qq][bb0];
      float w[2] = {wv.x, wv.y};
      float u[4] = {uv.x, uv.y, uv.z, uv.w};
#pragma unroll
      for (int aa = 0; aa < 2; ++aa)
#pragma unroll
        for (int cc = 0; cc < 4; ++cc)
          acc[aa][cc] = fmaf(w[aa], u[cc], acc[aa][cc]);
    }
    __syncthreads();
  }

#pragma unroll
  for (int aa = 0; aa < 2; ++aa) {
    int j = j0 + jj0 + aa;
#pragma unroll
    for (int cc = 0; cc < 4; ++cc) {
      int cb = cb0 + bb0 + cc;
      if (cb < cnt) {
        uint idx = (uint)(b_lo + cb) * NN + (uint)j;
        if (idx < out_capf) out[idx] = L.scale * acc[aa][cc];
      }
    }
  }
}

__global__ __launch_bounds__(256) void frft_gemm1(const float* __restrict__ x,
                                                  const float* __restrict__ order,
                                                  float* __restrict__ out,
                                                  uint x_cap, uint out_capf) {
  __shared__ float xrow[NN];
  __shared__ float xio[NN - 1];
  __shared__ float red[4][64];
  const int tid = threadIdx.x;
  const int j0 = blockIdx.x * 64;
  LitConsts L = get_lit(order);

#pragma unroll
  for (int e = 0; e < 16; ++e) {
    int i = tid + e * 256;
    xrow[i] = xload(x, (uint)255 * NN + (uint)i, x_cap);
  }
  __syncthreads();
#pragma unroll
  for (int m = 0; m < 16; ++m) {
    int s = tid + m * 256;
    if (s < NN - 1) {
      float a0 = 0.f;
      for (int i = 0; i < NN; ++i) {
        int t = s - i;
        float sgn = (t & 1) ? -0.63661977236758134f : 0.63661977236758134f;
        a0 = fmaf(xrow[i], __fdividef(sgn, (float)(2 * t + 1)), a0);
      }
      xio[s] = a0;
    }
  }
  __syncthreads();

  const int ty = tid >> 6, jj = tid & 63;
  const int j = j0 + jj;
  const int n = 2 * j - (NN - 1);
  const float base = fmaf(-L.q, (float)(n * n), L.pe);
  float acc = 0.f;
  int rend = (ty + 1) * 2048; if (rend > KK) rend = KK;
  for (int r = ty * 2048; r < rend; ++r) {
    int d = 2 * j - r;
    int k = r - (NN - 1);
    float ph = fmaf(L.c, (float)(d * d), fmaf(-L.q, (float)(k * k), base));
    float u = (r & 1) ? xio[r >> 1] : xrow[r >> 1];
    acc = fmaf(__cosf(ph), u, acc);
  }
  red[ty][jj] = acc;
  __syncthreads();
  if (ty == 0) {
    float t = red[0][jj] + red[1][jj] + red[2][jj] + red[3][jj];
    uint idx = (uint)255 * NN + (uint)j;
    if (idx < out_capf) out[idx] = L.scale * t;
  }
}

extern "C" void kernel_launch(void* const* d_in, const int* in_sizes, int n_in,
                              void* d_out, int out_size, void* d_ws, size_t ws_size,
                              hipStream_t stream) {
  const float* x     = (const float*)d_in[0];
  const float* order = (const float*)d_in[1];
  float* outf = (float*)d_out;
  const uint x_cap    = (uint)in_sizes[0];
  const uint out_capf = (uint)out_size;
  const size_t ws_halves = ws_size / 2;

  // ---- R21 conflict-free (both sides) LDS-staged MFMA path ----
  if (ws_size >= (size_t)NN * BB * 2 &&
      out_capf >= (uint)NN * BB && x_cap >= (uint)NN * BB) {
    _Float16* xiT = (_Float16*)d_ws;
    s1_v4<<<dim3(256), 1024, 0, stream>>>(x, xiT);
    s2_v4<<<dim3(256), 1024, 0, stream>>>(x, xiT, order, outf);
    return;
  }

  // ---- R13 proven fallback paths ----
  if (ws_halves >= (size_t)(NN - 1) * BB) {
    uint xi_cap = (uint)((size_t)(NN - 1) * BB);
    frft_interp<<<dim3(64, 4), 256, 0, stream>>>(x, (__half*)d_ws, 0, BB, xi_cap, x_cap);
    frft_gemm<<<dim3(NN / TJ, BB / TB), 256, 0, stream>>>(x, (__half*)d_ws, order, outf,
                                                          0, BB, xi_cap, x_cap, out_capf);
  } else {
    struct Chunk { int lo, cnt; };
    const Chunk ch[6] = { {0,170}, {170,57}, {227,19}, {246,6}, {252,2}, {254,1} };
    for (int i = 0; i < 6; ++i) {
      const Chunk& c = ch[i];
      uint off = (uint)(c.lo + c.cnt) * (uint)NN;
      __half* xp = (__half*)(outf + off);
      size_t need = (size_t)(NN - 1) * (size_t)c.cnt;
      size_t avail = (out_capf > off) ? (size_t)(out_capf - off) * 2 : 0;
      uint xi_cap = (uint)(need < avail ? need : avail);
      frft_interp<<<dim3(64, (unsigned)((c.cnt + 63) / 64)), 256, 0, stream>>>(
          x, xp, c.lo, c.cnt, xi_cap, x_cap);
      frft_gemm<<<dim3(NN / TJ, (unsigned)((c.cnt + TB - 1) / TB)), 256, 0, stream>>>(
          x, xp, order, outf, c.lo, c.cnt, xi_cap, x_cap, out_capf);
    }
    if (ws_halves >= (size_t)(NN - 1)) {
      uint xi_cap = (uint)(NN - 1);
      frft_interp<<<dim3(64, 1), 256, 0, stream>>>(x, (__half*)d_ws, 255, 1, xi_cap, x_cap);
      frft_gemm<<<dim3(NN / TJ, 1), 256, 0, stream>>>(x, (__half*)d_ws, order, outf,
                                                      255, 1, xi_cap, x_cap, out_capf);
    } else {
      frft_gemm1<<<64, 256, 0, stream>>>(x, order, outf, x_cap, out_capf);
    }
  }
}